// Round 7
// baseline (1242.821 us; speedup 1.0000x reference)
//
#include <hip/hip_runtime.h>

typedef unsigned long long ull;
typedef __bf16 bf16x8 __attribute__((ext_vector_type(8)));
typedef float f32x4 __attribute__((ext_vector_type(4)));

__device__ __forceinline__ float bf2f(unsigned short u) {
  union { unsigned int i; float f; } c; c.i = ((unsigned int)u) << 16; return c.f;
}
__device__ __forceinline__ unsigned short f2bf(float f) {
  union { float f; unsigned int i; } c; c.f = f;
  unsigned int u = c.i;
  u += 0x7fffu + ((u >> 16) & 1u);
  return (unsigned short)(u >> 16);
}

// ---- pack 4x [256,K] fp32 weights -> bf16 [1024,K] + bias concat ----------
__global__ __launch_bounds__(256) void pack_weights(
    const float* __restrict__ wq, const float* __restrict__ wk,
    const float* __restrict__ wv, const float* __restrict__ ws,
    const float* __restrict__ bq, const float* __restrict__ bk,
    const float* __restrict__ bv, const float* __restrict__ bs,
    unsigned short* __restrict__ Wcat, float* __restrict__ bcat, int logK) {
  int idx = blockIdx.x * 256 + threadIdx.x;
  if (idx < 1024) {
    int rr = idx >> 8, cc = idx & 255;
    const float* bp = (rr == 0) ? bq : (rr == 1) ? bk : (rr == 2) ? bv : bs;
    bcat[idx] = bp[cc];
  }
  int K = 1 << logK;
  if (idx >= (1024 << logK)) return;
  int o = idx >> logK, k = idx & (K - 1);
  int rr = o >> 8, oo = o & 255;
  const float* wp = (rr == 0) ? wq : (rr == 1) ? wk : (rr == 2) ? wv : ws;
  Wcat[idx] = f2bf(wp[oo * K + k]);
}

// ---- embedding gather: x[n, f*64+j] = emb[x_idx[n,f], j], fp32 -> bf16 ----
__global__ __launch_bounds__(256) void embed_gather(
    const int* __restrict__ x_idx, const float* __restrict__ emb,
    unsigned short* __restrict__ xbf, int total) {
  int idx = blockIdx.x * 256 + threadIdx.x;
  if (idx >= total) return;
  int node = idx >> 9, d = idx & 511, f = d >> 6, j = d & 63;
  int vi = x_idx[node * 8 + f];
  xbf[idx] = f2bf(emb[vi * 64 + j]);
}

// ---- CSR build ------------------------------------------------------------
__global__ __launch_bounds__(256) void count_dst(const int* __restrict__ dst,
                                                 int* __restrict__ counts, int E_) {
  int i = blockIdx.x * 256 + threadIdx.x;
  if (i < E_) atomicAdd(&counts[dst[i]], 1);
}

__global__ __launch_bounds__(256) void alloc_rows(const int* __restrict__ counts,
                                                  int* __restrict__ row_start,
                                                  int* __restrict__ cursor,
                                                  int* __restrict__ total, int n) {
  int i = blockIdx.x * 256 + threadIdx.x;
  int lane = threadIdx.x & 63;
  int c = (i < n) ? counts[i] : 0;
  int incl = c;
#pragma unroll
  for (int off = 1; off < 64; off <<= 1) {
    int t = __shfl_up(incl, off, 64);
    if (lane >= off) incl += t;
  }
  int base = 0;
  if (lane == 63) base = atomicAdd(total, incl);
  base = __shfl(base, 63, 64);
  int st = base + incl - c;
  if (i < n) { row_start[i] = st; cursor[i] = st; }
}

// scatter edges into CSR order; materialize permuted src/dst ids and attrs
__global__ __launch_bounds__(256) void scatter_edges(
    const int* __restrict__ dst, const int* __restrict__ srcA,
    const float* __restrict__ eattr, int* __restrict__ cursor,
    int* __restrict__ srcs, int* __restrict__ dsts,
    float* __restrict__ ea_perm, int E_) {
  int i = blockIdx.x * 256 + threadIdx.x;
  if (i >= E_) return;
  int d = dst[i];
  int p = atomicAdd(&cursor[d], 1);
  srcs[p] = srcA[i];
  dsts[p] = d;
  const float* ea = eattr + (size_t)i * 6;
  float* eo = ea_perm + (size_t)p * 6;
  eo[0] = ea[0]; eo[1] = ea[1]; eo[2] = ea[2];
  eo[3] = ea[3]; eo[4] = ea[4]; eo[5] = ea[5];
}

// ---- fused QKVS GEMM: [N,K]bf16 x [1024,K]bf16 -> q,k,v bf16 + skip fp32 --
// q pre-scaled by 1/16 (1/sqrt(DH)).
// XCD-aware remap: linear grid; XCD (bid%8) owns a CONTIGUOUS row-block
// range and iterates the 16 col-tiles innermost -> each 128-row X panel is
// fetched into one XCD L2 once and reused 16x (was: every XCD fetched all
// of X -> FETCH_SIZE = 8x51MB = 410MB, latency-bound on far fetches).
template <int K>
__global__ __launch_bounds__(256) void gemm_qkvs(
    const unsigned short* __restrict__ X, const unsigned short* __restrict__ W,
    const float* __restrict__ bcat,
    unsigned short* __restrict__ qout, unsigned short* __restrict__ kout,
    unsigned short* __restrict__ vout, float* __restrict__ sout,
    int Nn, int nrb) {
  const int l = blockIdx.x;
  const int xcd = l & 7, j = l >> 3;
  const int q = nrb >> 3, r = nrb & 7;
  const int cnt = q + (xcd < r ? 1 : 0);
  const int lrb = j >> 4, colt = j & 15;
  if (lrb >= cnt) return;
  const int m_blk = xcd * q + min(xcd, r) + lrb;

  const int wid = threadIdx.x >> 6;
  const int lane = threadIdx.x & 63;
  const int quad = lane >> 4, lm = lane & 15;
  const int m_base = m_blk * 128 + wid * 32;
  const int n_base = colt * 64;
  const int r0 = min(m_base + lm, Nn - 1);
  const int r1 = min(m_base + 16 + lm, Nn - 1);
  const bf16x8* a0p = (const bf16x8*)(X + (size_t)r0 * K + quad * 8);
  const bf16x8* a1p = (const bf16x8*)(X + (size_t)r1 * K + quad * 8);
  const bf16x8* b0p = (const bf16x8*)(W + (size_t)(n_base + lm) * K + quad * 8);
  const bf16x8* b1p = (const bf16x8*)(W + (size_t)(n_base + 16 + lm) * K + quad * 8);
  const bf16x8* b2p = (const bf16x8*)(W + (size_t)(n_base + 32 + lm) * K + quad * 8);
  const bf16x8* b3p = (const bf16x8*)(W + (size_t)(n_base + 48 + lm) * K + quad * 8);
  f32x4 acc[2][4] = {};
#pragma unroll 4
  for (int k0 = 0; k0 < K; k0 += 32) {
    const int ko = k0 >> 3;  // 32 shorts = 4 bf16x8 units
    bf16x8 a0 = a0p[ko], a1 = a1p[ko];
    bf16x8 b0 = b0p[ko], b1 = b1p[ko], b2 = b2p[ko], b3 = b3p[ko];
    acc[0][0] = __builtin_amdgcn_mfma_f32_16x16x32_bf16(a0, b0, acc[0][0], 0, 0, 0);
    acc[0][1] = __builtin_amdgcn_mfma_f32_16x16x32_bf16(a0, b1, acc[0][1], 0, 0, 0);
    acc[0][2] = __builtin_amdgcn_mfma_f32_16x16x32_bf16(a0, b2, acc[0][2], 0, 0, 0);
    acc[0][3] = __builtin_amdgcn_mfma_f32_16x16x32_bf16(a0, b3, acc[0][3], 0, 0, 0);
    acc[1][0] = __builtin_amdgcn_mfma_f32_16x16x32_bf16(a1, b0, acc[1][0], 0, 0, 0);
    acc[1][1] = __builtin_amdgcn_mfma_f32_16x16x32_bf16(a1, b1, acc[1][1], 0, 0, 0);
    acc[1][2] = __builtin_amdgcn_mfma_f32_16x16x32_bf16(a1, b2, acc[1][2], 0, 0, 0);
    acc[1][3] = __builtin_amdgcn_mfma_f32_16x16x32_bf16(a1, b3, acc[1][3], 0, 0, 0);
  }
#pragma unroll
  for (int mi = 0; mi < 2; mi++) {
#pragma unroll
    for (int r2 = 0; r2 < 4; r2++) {
      int row = m_base + mi * 16 + quad * 4 + r2;
      if (row >= Nn) continue;
      size_t rb = (size_t)row * 256;
#pragma unroll
      for (int ni = 0; ni < 4; ni++) {
        int col = n_base + ni * 16 + lm;
        float v = acc[mi][ni][r2] + bcat[col];
        int reg = col >> 8, c = col & 255;
        if (reg == 0)       qout[rb + c] = f2bf(v * 0.0625f);
        else if (reg == 1)  kout[rb + c] = f2bf(v);
        else if (reg == 2)  vout[rb + c] = f2bf(v);
        else                sout[rb + c] = v;
      }
    }
  }
}

// ---- node_prep: z[n] = We^T q[n] (6), c[n] = q[n].be -> zc[n][8] ----------
__global__ __launch_bounds__(256) void node_prep(
    const unsigned short* __restrict__ qv,
    const float* __restrict__ we, const float* __restrict__ be,
    float* __restrict__ zc, int Nn) {
  __shared__ float we_s[1536];
  __shared__ float be_s[256];
  for (int i = threadIdx.x; i < 1536; i += 256) we_s[i] = we[i];
  be_s[threadIdx.x] = be[threadIdx.x];
  __syncthreads();
  int wid = threadIdx.x >> 6, lane = threadIdx.x & 63;
  int n = blockIdx.x * 4 + wid;
  if (n >= Nn) return;
  int j0 = lane * 4;
  ull uq = *(const ull*)(qv + (size_t)n * 256 + j0);
  float q0 = bf2f((unsigned short)uq), q1 = bf2f((unsigned short)(uq >> 16));
  float q2 = bf2f((unsigned short)(uq >> 32)), q3 = bf2f((unsigned short)(uq >> 48));
  float part[7];
#pragma unroll
  for (int t = 0; t < 6; t++) {
    part[t] = we_s[(j0 + 0) * 6 + t] * q0 + we_s[(j0 + 1) * 6 + t] * q1
            + we_s[(j0 + 2) * 6 + t] * q2 + we_s[(j0 + 3) * 6 + t] * q3;
  }
  part[6] = be_s[j0] * q0 + be_s[j0 + 1] * q1 + be_s[j0 + 2] * q2 + be_s[j0 + 3] * q3;
#pragma unroll
  for (int off = 32; off > 0; off >>= 1) {
#pragma unroll
    for (int t = 0; t < 7; t++) part[t] += __shfl_xor(part[t], off, 64);
  }
  if (lane == 0) {
    float* zp = zc + (size_t)n * 8;
#pragma unroll
    for (int t = 0; t < 7; t++) zp[t] = part[t];
    zp[7] = 0.f;
  }
}

__device__ __forceinline__ float dot4(ull uq, ull uk) {
  return bf2f((unsigned short)uq) * bf2f((unsigned short)uk)
       + bf2f((unsigned short)(uq >> 16)) * bf2f((unsigned short)(uk >> 16))
       + bf2f((unsigned short)(uq >> 32)) * bf2f((unsigned short)(uk >> 32))
       + bf2f((unsigned short)(uq >> 48)) * bf2f((unsigned short)(uk >> 48));
}

#define SEL8_I(a, t) ((t)==0?(a)[0]:(t)==1?(a)[1]:(t)==2?(a)[2]:(t)==3?(a)[3]:(t)==4?(a)[4]:(t)==5?(a)[5]:(t)==6?(a)[6]:(a)[7])

// ---- P1: edge-parallel logits = q[dst].k[src] + z[dst].u + c[dst] ---------
__global__ __launch_bounds__(256) void edge_logits(
    const int* __restrict__ srcs, const int* __restrict__ dsts,
    const float* __restrict__ ea_perm,
    const unsigned short* __restrict__ qv, const unsigned short* __restrict__ kv,
    const float* __restrict__ zc, int E_, float* __restrict__ logits) {
  int wid = threadIdx.x >> 6, lane = threadIdx.x & 63;
  int p0 = (blockIdx.x * 4 + wid) * 8;
  if (p0 >= E_) return;
  int j0 = lane * 4;
  int s_[8], d_[8];
  if (p0 + 8 <= E_) {
    int4 sa = *(const int4*)(srcs + p0), sb = *(const int4*)(srcs + p0 + 4);
    int4 da = *(const int4*)(dsts + p0), db = *(const int4*)(dsts + p0 + 4);
    s_[0] = sa.x; s_[1] = sa.y; s_[2] = sa.z; s_[3] = sa.w;
    s_[4] = sb.x; s_[5] = sb.y; s_[6] = sb.z; s_[7] = sb.w;
    d_[0] = da.x; d_[1] = da.y; d_[2] = da.z; d_[3] = da.w;
    d_[4] = db.x; d_[5] = db.y; d_[6] = db.z; d_[7] = db.w;
  } else {
#pragma unroll
    for (int t = 0; t < 8; t++) {
      int pp = min(p0 + t, E_ - 1);
      s_[t] = srcs[pp]; d_[t] = dsts[pp];
    }
  }
  ull uk[8], uq[8];
#pragma unroll
  for (int t = 0; t < 8; t++) uk[t] = *(const ull*)(kv + (size_t)s_[t] * 256 + j0);
#pragma unroll
  for (int t = 0; t < 8; t++) uq[t] = *(const ull*)(qv + (size_t)d_[t] * 256 + j0);
  float pv[8];
#pragma unroll
  for (int t = 0; t < 8; t++) pv[t] = dot4(uq[t], uk[t]);
#pragma unroll
  for (int off = 32; off > 0; off >>= 1) {
#pragma unroll
    for (int t = 0; t < 8; t++) pv[t] += __shfl_xor(pv[t], off, 64);
  }
  // lane t (t<8) finalizes edge t: + z[dst].u + c[dst]
  if (lane < 8 && p0 + lane < E_) {
    int t = lane;
    int dd = SEL8_I(d_, t);
    float pvt = SEL8_I(pv, t);
    const float* zp = zc + (size_t)dd * 8;
    const float* u = ea_perm + (size_t)(p0 + t) * 6;
    float zd = zp[0] * u[0] + zp[1] * u[1] + zp[2] * u[2]
             + zp[3] * u[3] + zp[4] * u[4] + zp[5] * u[5] + zp[6];
    logits[p0 + t] = pvt + zd;
  }
}

// ---- P2: per-node softmax; overwrite logits with weights; also ubar -------
// ubar[n][0..5] = sum_p w_p * u_p (direct store, no atomics).
__global__ __launch_bounds__(256) void node_softmax(
    const int* __restrict__ row_start, const int* __restrict__ counts,
    const float* __restrict__ ea_perm,
    float* __restrict__ logits, float* __restrict__ ubar, int Nn) {
  int wid = threadIdx.x >> 6, lane = threadIdx.x & 63;
  int n = blockIdx.x * 4 + wid;
  if (n >= Nn) return;
  int beg = row_start[n], cnt = counts[n];
  if (cnt == 0) return;
  float lm = -INFINITY;
  for (int b = lane; b < cnt; b += 64) lm = fmaxf(lm, logits[beg + b]);
#pragma unroll
  for (int off = 32; off > 0; off >>= 1) lm = fmaxf(lm, __shfl_xor(lm, off, 64));
  float se = 0.f;
  for (int b = lane; b < cnt; b += 64) se += __expf(logits[beg + b] - lm);
#pragma unroll
  for (int off = 32; off > 0; off >>= 1) se += __shfl_xor(se, off, 64);
  float inv = 1.f / se;
  float u0 = 0.f, u1 = 0.f, u2 = 0.f, u3 = 0.f, u4 = 0.f, u5 = 0.f;
  for (int b = lane; b < cnt; b += 64) {
    int p = beg + b;
    float w = __expf(logits[p] - lm) * inv;
    logits[p] = w;
    const float* up = ea_perm + (size_t)p * 6;
    u0 += w * up[0]; u1 += w * up[1]; u2 += w * up[2];
    u3 += w * up[3]; u4 += w * up[4]; u5 += w * up[5];
  }
#pragma unroll
  for (int off = 32; off > 0; off >>= 1) {
    u0 += __shfl_xor(u0, off, 64); u1 += __shfl_xor(u1, off, 64);
    u2 += __shfl_xor(u2, off, 64); u3 += __shfl_xor(u3, off, 64);
    u4 += __shfl_xor(u4, off, 64); u5 += __shfl_xor(u5, off, 64);
  }
  if (lane == 0) {
    float* up = ubar + (size_t)n * 8;
    up[0] = u0; up[1] = u1; up[2] = u2; up[3] = u3; up[4] = u4; up[5] = u5;
  }
}

// ---- P3: edge-parallel SEGMENTED weighted v-sum (dsts sorted by CSR) ------
// 32 consecutive edges per wave. Complete segments -> direct float4 store;
// boundary segments -> atomicAdd (h_acc pre-zeroed). ~4.8M atomics.
#define CHK 32
__global__ __launch_bounds__(256) void edge_seg(
    const int* __restrict__ srcs, const int* __restrict__ dsts,
    const float* __restrict__ wgt,
    const unsigned short* __restrict__ vv, int E_,
    float* __restrict__ h_acc) {
  int wid = threadIdx.x >> 6, lane = threadIdx.x & 63;
  int p0 = (blockIdx.x * 4 + wid) * CHK;
  if (p0 >= E_) return;
  int pe = min(CHK, E_ - p0);
  int j0 = lane * 4;
  int d_before = (p0 > 0) ? dsts[p0 - 1] : -1;
  int d_after  = (p0 + CHK < E_) ? dsts[p0 + CHK] : -1;
  int dd[CHK], ss[CHK];
  float w_[CHK];
  if (pe == CHK) {
#pragma unroll
    for (int t4 = 0; t4 < CHK; t4 += 4) {
      int4 dv = *(const int4*)(dsts + p0 + t4);
      int4 sv = *(const int4*)(srcs + p0 + t4);
      float4 wv = *(const float4*)(wgt + p0 + t4);
      dd[t4] = dv.x; dd[t4 + 1] = dv.y; dd[t4 + 2] = dv.z; dd[t4 + 3] = dv.w;
      ss[t4] = sv.x; ss[t4 + 1] = sv.y; ss[t4 + 2] = sv.z; ss[t4 + 3] = sv.w;
      w_[t4] = wv.x; w_[t4 + 1] = wv.y; w_[t4 + 2] = wv.z; w_[t4 + 3] = wv.w;
    }
  } else {
#pragma unroll
    for (int t = 0; t < CHK; t++) {
      int pp = min(p0 + t, E_ - 1);
      dd[t] = dsts[pp]; ss[t] = srcs[pp]; w_[t] = wgt[pp];
    }
  }
  ull uv[CHK];
#pragma unroll
  for (int t = 0; t < CHK; t++)
    uv[t] = *(const ull*)(vv + (size_t)ss[t] * 256 + j0);
  float a0 = 0.f, a1 = 0.f, a2 = 0.f, a3 = 0.f;
  int cur_d = dd[0];
#pragma unroll
  for (int t = 0; t < CHK; t++) {
    if (t >= pe) break;
    int d = dd[t];
    if (d != cur_d) {
      bool partial = (cur_d == d_before) || (cur_d == d_after);
      float* hp = h_acc + (size_t)cur_d * 256 + j0;
      if (partial) {
        atomicAdd(hp + 0, a0); atomicAdd(hp + 1, a1);
        atomicAdd(hp + 2, a2); atomicAdd(hp + 3, a3);
      } else {
        float4 o; o.x = a0; o.y = a1; o.z = a2; o.w = a3;
        *(float4*)hp = o;
      }
      a0 = a1 = a2 = a3 = 0.f;
      cur_d = d;
    }
    float ww = w_[t];
    a0 += ww * bf2f((unsigned short)uv[t]);
    a1 += ww * bf2f((unsigned short)(uv[t] >> 16));
    a2 += ww * bf2f((unsigned short)(uv[t] >> 32));
    a3 += ww * bf2f((unsigned short)(uv[t] >> 48));
  }
  {
    bool partial = (cur_d == d_before) || (cur_d == d_after);
    float* hp = h_acc + (size_t)cur_d * 256 + j0;
    if (partial) {
      atomicAdd(hp + 0, a0); atomicAdd(hp + 1, a1);
      atomicAdd(hp + 2, a2); atomicAdd(hp + 3, a3);
    } else {
      float4 o; o.x = a0; o.y = a1; o.z = a2; o.w = a3;
      *(float4*)hp = o;
    }
  }
}

// ---- P4: streaming finalize: h = relu(h_acc + We*ubar + be*[cnt>0] + skip)
// mode 0: write h bf16 to hout. mode 1: write h fp32 IN PLACE into h_acc.
__global__ __launch_bounds__(256) void node_finalize(
    float* __restrict__ h_acc, const float* __restrict__ ubar,
    const int* __restrict__ counts, const float* __restrict__ skipv,
    const float* __restrict__ we, const float* __restrict__ be,
    int Nn, int mode,
    unsigned short* __restrict__ hout) {
  __shared__ float we_s[1536];
  __shared__ float be_s[256];
  for (int i = threadIdx.x; i < 1536; i += 256) we_s[i] = we[i];
  be_s[threadIdx.x] = be[threadIdx.x];
  __syncthreads();
  int wid = threadIdx.x >> 6, lane = threadIdx.x & 63;
  int n = blockIdx.x * 4 + wid;
  if (n >= Nn) return;
  int j0 = lane * 4;
  float4 ha = *(const float4*)(h_acc + (size_t)n * 256 + j0);
  float4 skv = *(const float4*)(skipv + (size_t)n * 256 + j0);
  int cnt = counts[n];
  float e[4] = {0.f, 0.f, 0.f, 0.f};
  if (cnt > 0) {
    float4 u0 = *(const float4*)(ubar + (size_t)n * 8);
    float4 u1 = *(const float4*)(ubar + (size_t)n * 8 + 4);
#pragma unroll
    for (int r = 0; r < 4; r++) {
      int d = j0 + r;
      e[r] = be_s[d]
           + we_s[d * 6 + 0] * u0.x + we_s[d * 6 + 1] * u0.y + we_s[d * 6 + 2] * u0.z
           + we_s[d * 6 + 3] * u0.w + we_s[d * 6 + 4] * u1.x + we_s[d * 6 + 5] * u1.y;
    }
  }
  float h0 = fmaxf(ha.x + e[0] + skv.x, 0.f);
  float h1 = fmaxf(ha.y + e[1] + skv.y, 0.f);
  float h2 = fmaxf(ha.z + e[2] + skv.z, 0.f);
  float h3 = fmaxf(ha.w + e[3] + skv.w, 0.f);
  if (mode == 0) {
    ull hv = (ull)f2bf(h0) | ((ull)f2bf(h1) << 16) | ((ull)f2bf(h2) << 32) | ((ull)f2bf(h3) << 48);
    *(ull*)(hout + (size_t)n * 256 + j0) = hv;
  } else {
    float4 o; o.x = h0; o.y = h1; o.z = h2; o.w = h3;
    *(float4*)(h_acc + (size_t)n * 256 + j0) = o;
  }
}

// ---- P5: segmented pooling over sorted batch (contiguous node ranges) -----
__global__ __launch_bounds__(256) void pool_reduce(
    const float* __restrict__ hfin, const int* __restrict__ batch, int Nn,
    float* __restrict__ gap, unsigned int* __restrict__ gmp) {
  int g = blockIdx.x, s = blockIdx.y, t = threadIdx.x;
  __shared__ int st_s, en_s;
  if (t == 0) {
    int lo = 0, hi = Nn;
    while (lo < hi) { int mid = (lo + hi) >> 1; if (batch[mid] < g) lo = mid + 1; else hi = mid; }
    st_s = lo;
    lo = 0; hi = Nn;
    while (lo < hi) { int mid = (lo + hi) >> 1; if (batch[mid] < g + 1) lo = mid + 1; else hi = mid; }
    en_s = lo;
  }
  __syncthreads();
  int st = st_s, en = en_s;
  int len = en - st;
  if (len <= 0) return;
  int nsplit = gridDim.y;
  int chunk = (len + nsplit - 1) / nsplit;
  int a = st + s * chunk;
  int b = min(a + chunk, en);
  if (a >= b) return;
  float acc = 0.f, mx = 0.f;  // h >= 0 (relu)
  for (int n = a; n < b; n++) {
    float v = hfin[(size_t)n * 256 + t];
    acc += v;
    mx = fmaxf(mx, v);
  }
  atomicAdd(&gap[(size_t)g * 256 + t], acc);
  atomicMax(&gmp[(size_t)g * 256 + t], __float_as_uint(mx));
}

// ---- per-graph pooling finalize + 3-layer MLP + sigmoid -------------------
__global__ __launch_bounds__(256) void pool_mlp(
    const float* __restrict__ gap, const unsigned int* __restrict__ gmp,
    const int* __restrict__ batch, int Nn,
    const float* __restrict__ w1, const float* __restrict__ b1,
    const float* __restrict__ w2, const float* __restrict__ b2,
    const float* __restrict__ w3, const float* __restrict__ b3,
    float* __restrict__ out) {
  int g = blockIdx.x, t = threadIdx.x;
  __shared__ float r[512];
  __shared__ float o1[256];
  __shared__ float o2[128];
  __shared__ float red[256];
  __shared__ int cnt_s;
  if (t == 0) {
    int lo = 0, hi = Nn;
    while (lo < hi) { int mid = (lo + hi) >> 1; if (batch[mid] < g) lo = mid + 1; else hi = mid; }
    int st = lo;
    lo = 0; hi = Nn;
    while (lo < hi) { int mid = (lo + hi) >> 1; if (batch[mid] < g + 1) lo = mid + 1; else hi = mid; }
    cnt_s = lo - st;
  }
  __syncthreads();
  float inv = 1.f / fmaxf((float)cnt_s, 1.f);
  r[t] = gap[(size_t)g * 256 + t] * inv;
  r[256 + t] = __uint_as_float(gmp[(size_t)g * 256 + t]);
  __syncthreads();
  {
    float a = b1[t];
    const float* wr = w1 + (size_t)t * 512;
    for (int k = 0; k < 512; k++) a += wr[k] * r[k];
    o1[t] = fmaxf(a, 0.f);
  }
  __syncthreads();
  if (t < 128) {
    float a = b2[t];
    const float* wr = w2 + (size_t)t * 256;
    for (int k = 0; k < 256; k++) a += wr[k] * o1[k];
    o2[t] = fmaxf(a, 0.f);
  }
  __syncthreads();
  red[t] = (t < 128) ? w3[t] * o2[t] : 0.f;
  __syncthreads();
  for (int s = 128; s > 0; s >>= 1) {
    if (t < s) red[t] += red[t + s];
    __syncthreads();
  }
  if (t == 0) out[g] = 1.f / (1.f + expf(-(red[0] + b3[0])));
}

// ---------------------------------------------------------------------------
extern "C" void kernel_launch(void* const* d_in, const int* in_sizes, int n_in,
                              void* d_out, int out_size, void* d_ws, size_t ws_size,
                              hipStream_t stream) {
  const int* x_idx      = (const int*)d_in[0];
  const int* edge_index = (const int*)d_in[1];
  const float* eattr    = (const float*)d_in[2];
  const int* batch      = (const int*)d_in[3];
  const float* emb      = (const float*)d_in[4];
  const float* c1_wq = (const float*)d_in[5],  *c1_bq = (const float*)d_in[6];
  const float* c1_wk = (const float*)d_in[7],  *c1_bk = (const float*)d_in[8];
  const float* c1_wv = (const float*)d_in[9],  *c1_bv = (const float*)d_in[10];
  const float* c1_we = (const float*)d_in[11], *c1_be = (const float*)d_in[12];
  const float* c1_ws = (const float*)d_in[13], *c1_bs = (const float*)d_in[14];
  const float* c2_wq = (const float*)d_in[15], *c2_bq = (const float*)d_in[16];
  const float* c2_wk = (const float*)d_in[17], *c2_bk = (const float*)d_in[18];
  const float* c2_wv = (const float*)d_in[19], *c2_bv = (const float*)d_in[20];
  const float* c2_we = (const float*)d_in[21], *c2_be = (const float*)d_in[22];
  const float* c2_ws = (const float*)d_in[23], *c2_bs = (const float*)d_in[24];
  const float* w1 = (const float*)d_in[25], *b1 = (const float*)d_in[26];
  const float* w2 = (const float*)d_in[27], *b2 = (const float*)d_in[28];
  const float* w3 = (const float*)d_in[29], *b3 = (const float*)d_in[30];

  const int Nn = in_sizes[3];        // 50000
  const int Ee = in_sizes[1] / 2;    // 300000

  char* ws = (char*)d_ws;
  size_t off = 0;
  auto alloc = [&](size_t bytes) -> void* {
    void* p = ws + off;
    off += (bytes + 255) & ~(size_t)255;
    return p;
  };
  unsigned short* xbf   = (unsigned short*)alloc((size_t)Nn * 512 * 2);
  unsigned short* qbf   = (unsigned short*)alloc((size_t)Nn * 256 * 2);
  unsigned short* kbf   = (unsigned short*)alloc((size_t)Nn * 256 * 2);
  unsigned short* vbf   = (unsigned short*)alloc((size_t)Nn * 256 * 2);
  float*          skipf = (float*)alloc((size_t)Nn * 256 * 4);
  unsigned short* h1bf  = (unsigned short*)alloc((size_t)Nn * 256 * 2);
  unsigned short* Wcat1 = (unsigned short*)alloc((size_t)1024 * 512 * 2);
  float*          bcat1 = (float*)alloc(1024 * 4);
  unsigned short* Wcat2 = (unsigned short*)alloc((size_t)1024 * 256 * 2);
  float*          bcat2 = (float*)alloc(1024 * 4);
  int*            counts    = (int*)alloc((size_t)Nn * 4);
  int*            row_start = (int*)alloc((size_t)Nn * 4);
  int*            cursor    = (int*)alloc((size_t)Nn * 4);
  int*            srcs      = (int*)alloc((size_t)Ee * 4);
  int*            dsts      = (int*)alloc((size_t)Ee * 4);
  float*          ea_perm   = (float*)alloc((size_t)Ee * 6 * 4);
  float*          logits    = (float*)alloc((size_t)Ee * 4);   // becomes weights
  float*          zc        = (float*)alloc((size_t)Nn * 8 * 4);
  float*          ubar      = (float*)alloc((size_t)Nn * 8 * 4);
  int*            total     = (int*)alloc(256);
  float*          gap       = (float*)alloc((size_t)64 * 256 * 4);
  unsigned int*   gmp       = (unsigned int*)alloc((size_t)64 * 256 * 4);
  // h_acc (50k x 256 fp32 = 51.2 MB) ALIASES xbf (same size): xbf is dead
  // after the first gemm; h_acc is first touched after it. ~221 MB total.
  float* h_acc = (float*)xbf;

  const int* srcA = edge_index;
  const int* dstA = edge_index + Ee;

  hipMemsetAsync(counts, 0, (size_t)Nn * 4, stream);
  hipMemsetAsync(total, 0, 4, stream);
  hipMemsetAsync(gap, 0, (size_t)64 * 256 * 4, stream);
  hipMemsetAsync(gmp, 0, (size_t)64 * 256 * 4, stream);

  pack_weights<<<(1024 * 512 + 255) / 256, 256, 0, stream>>>(
      c1_wq, c1_wk, c1_wv, c1_ws, c1_bq, c1_bk, c1_bv, c1_bs, Wcat1, bcat1, 9);
  pack_weights<<<(1024 * 256 + 255) / 256, 256, 0, stream>>>(
      c2_wq, c2_wk, c2_wv, c2_ws, c2_bq, c2_bk, c2_bv, c2_bs, Wcat2, bcat2, 8);
  embed_gather<<<((Nn * 512) + 255) / 256, 256, 0, stream>>>(x_idx, emb, xbf, Nn * 512);
  count_dst<<<(Ee + 255) / 256, 256, 0, stream>>>(dstA, counts, Ee);
  alloc_rows<<<(Nn + 255) / 256, 256, 0, stream>>>(counts, row_start, cursor, total, Nn);
  scatter_edges<<<(Ee + 255) / 256, 256, 0, stream>>>(dstA, srcA, eattr, cursor,
                                                      srcs, dsts, ea_perm, Ee);

  // XCD-aware gemm grid: 8 XCD groups x max-row-blocks-per-XCD x 16 col-tiles
  const int nrb = (Nn + 127) / 128;                 // 391 row-blocks
  const int rbmax = nrb / 8 + ((nrb % 8) ? 1 : 0);  // 49
  const int ggrid = 8 * rbmax * 16;                 // 6272
  const int egrid = (Ee + 31) / 32;        // 4 waves/block x 8 edges/wave
  const int sgrid = (Ee + CHK * 4 - 1) / (CHK * 4);  // 4 waves x 32 edges
  const int ngrid = (Nn + 3) / 4;

  // layer 1
  gemm_qkvs<512><<<ggrid, 256, 0, stream>>>(xbf, Wcat1, bcat1, qbf, kbf, vbf,
                                            skipf, Nn, nrb);
  node_prep<<<ngrid, 256, 0, stream>>>(qbf, c1_we, c1_be, zc, Nn);
  edge_logits<<<egrid, 256, 0, stream>>>(srcs, dsts, ea_perm, qbf, kbf, zc, Ee, logits);
  node_softmax<<<ngrid, 256, 0, stream>>>(row_start, counts, ea_perm, logits, ubar, Nn);
  hipMemsetAsync(h_acc, 0, (size_t)Nn * 256 * 4, stream);   // xbf dead now
  edge_seg<<<sgrid, 256, 0, stream>>>(srcs, dsts, logits, vbf, Ee, h_acc);
  node_finalize<<<ngrid, 256, 0, stream>>>(h_acc, ubar, counts, skipf,
                                           c1_we, c1_be, Nn, 0, h1bf);

  // layer 2
  gemm_qkvs<256><<<ggrid, 256, 0, stream>>>(h1bf, Wcat2, bcat2, qbf, kbf, vbf,
                                            skipf, Nn, nrb);
  node_prep<<<ngrid, 256, 0, stream>>>(qbf, c2_we, c2_be, zc, Nn);
  edge_logits<<<egrid, 256, 0, stream>>>(srcs, dsts, ea_perm, qbf, kbf, zc, Ee, logits);
  node_softmax<<<ngrid, 256, 0, stream>>>(row_start, counts, ea_perm, logits, ubar, Nn);
  hipMemsetAsync(h_acc, 0, (size_t)Nn * 256 * 4, stream);
  edge_seg<<<sgrid, 256, 0, stream>>>(srcs, dsts, logits, vbf, Ee, h_acc);
  node_finalize<<<ngrid, 256, 0, stream>>>(h_acc, ubar, counts, skipf,
                                           c2_we, c2_be, Nn, 1, nullptr);

  // segmented pooling (batch sorted -> contiguous ranges), then MLP
  dim3 pg(64, 16);
  pool_reduce<<<pg, 256, 0, stream>>>(h_acc, batch, Nn, gap, gmp);
  pool_mlp<<<64, 256, 0, stream>>>(gap, gmp, batch, Nn, w1, b1, w2, b2, w3, b3,
                                   (float*)d_out);
}

// Round 9
// 1018.826 us; speedup vs baseline: 1.2199x; 1.2199x over previous
//
#include <hip/hip_runtime.h>

typedef unsigned long long ull;
typedef __bf16 bf16x8 __attribute__((ext_vector_type(8)));
typedef float f32x4 __attribute__((ext_vector_type(4)));

__device__ __forceinline__ float bf2f(unsigned short u) {
  union { unsigned int i; float f; } c; c.i = ((unsigned int)u) << 16; return c.f;
}
__device__ __forceinline__ unsigned short f2bf(float f) {
  union { float f; unsigned int i; } c; c.f = f;
  unsigned int u = c.i;
  u += 0x7fffu + ((u >> 16) & 1u);
  return (unsigned short)(u >> 16);
}

// ---- pack 4x [256,K] fp32 weights -> bf16 B-FRAGMENT-ORDER + bias concat --
// Layout: Wcat[colt][ks][lane][rg][kj] (shorts), lane=quad*16+lm:
//   element = W[colt*64 + rg*16 + lm][ks*32 + quad*8 + kj]
// so in gemm, lane reads its 4 b-frags as 64 CONTIGUOUS bytes.
__global__ __launch_bounds__(256) void pack_weights(
    const float* __restrict__ wq, const float* __restrict__ wk,
    const float* __restrict__ wv, const float* __restrict__ ws,
    const float* __restrict__ bq, const float* __restrict__ bk,
    const float* __restrict__ bv, const float* __restrict__ bs,
    unsigned short* __restrict__ Wcat, float* __restrict__ bcat, int logK) {
  int idx = blockIdx.x * 256 + threadIdx.x;
  if (idx < 1024) {
    int rr = idx >> 8, cc = idx & 255;
    const float* bp = (rr == 0) ? bq : (rr == 1) ? bk : (rr == 2) ? bv : bs;
    bcat[idx] = bp[cc];
  }
  int K = 1 << logK;
  if (idx >= (1024 << logK)) return;
  int kj = idx & 7, rg = (idx >> 3) & 3, lane = (idx >> 5) & 63;
  int ksbits = logK - 5;
  int ks = (idx >> 11) & ((1 << ksbits) - 1);
  int colt = idx >> (11 + ksbits);
  int quad = lane >> 4, lm = lane & 15;
  int o = colt * 64 + rg * 16 + lm;
  int k = ks * 32 + quad * 8 + kj;
  int rr = o >> 8, oo = o & 255;
  const float* wp = (rr == 0) ? wq : (rr == 1) ? wk : (rr == 2) ? wv : ws;
  Wcat[idx] = f2bf(wp[oo * K + k]);
}

// ---- embedding gather -> A-FRAGMENT-ORDER xbf (K=512) ---------------------
// element (n, d): addr = ((n32*16 + ks)*64 + quad*16+lm)*16 + half*8 + kj
//   n32=n>>5, lm=n&15, half=(n>>4)&1, ks=d>>5, quad=(d>>3)&3, kj=d&7
__global__ __launch_bounds__(256) void embed_gather(
    const int* __restrict__ x_idx, const float* __restrict__ emb,
    unsigned short* __restrict__ xbf, int total) {
  int idx = blockIdx.x * 256 + threadIdx.x;
  if (idx >= total) return;
  int n = idx >> 9, d = idx & 511, f = d >> 6, j = d & 63;
  int vi = x_idx[n * 8 + f];
  int n32 = n >> 5, lm = n & 15, half = (n >> 4) & 1;
  int ks = d >> 5, quad = (d >> 3) & 3, kj = d & 7;
  size_t a = (((size_t)n32 * 16 + ks) * 64 + quad * 16 + lm) * 16 + half * 8 + kj;
  xbf[a] = f2bf(emb[vi * 64 + j]);
}

// ---- CSR build ------------------------------------------------------------
__global__ __launch_bounds__(256) void count_dst(const int* __restrict__ dst,
                                                 int* __restrict__ counts, int E_) {
  int i = blockIdx.x * 256 + threadIdx.x;
  if (i < E_) atomicAdd(&counts[dst[i]], 1);
}

__global__ __launch_bounds__(256) void alloc_rows(const int* __restrict__ counts,
                                                  int* __restrict__ row_start,
                                                  int* __restrict__ cursor,
                                                  int* __restrict__ total, int n) {
  int i = blockIdx.x * 256 + threadIdx.x;
  int lane = threadIdx.x & 63;
  int c = (i < n) ? counts[i] : 0;
  int incl = c;
#pragma unroll
  for (int off = 1; off < 64; off <<= 1) {
    int t = __shfl_up(incl, off, 64);
    if (lane >= off) incl += t;
  }
  int base = 0;
  if (lane == 63) base = atomicAdd(total, incl);
  base = __shfl(base, 63, 64);
  int st = base + incl - c;
  if (i < n) { row_start[i] = st; cursor[i] = st; }
}

// scatter edges into CSR order; materialize permuted src/dst ids and attrs
__global__ __launch_bounds__(256) void scatter_edges(
    const int* __restrict__ dst, const int* __restrict__ srcA,
    const float* __restrict__ eattr, int* __restrict__ cursor,
    int* __restrict__ srcs, int* __restrict__ dsts,
    float* __restrict__ ea_perm, int E_) {
  int i = blockIdx.x * 256 + threadIdx.x;
  if (i >= E_) return;
  int d = dst[i];
  int p = atomicAdd(&cursor[d], 1);
  srcs[p] = srcA[i];
  dsts[p] = d;
  const float* ea = eattr + (size_t)i * 6;
  float* eo = ea_perm + (size_t)p * 6;
  eo[0] = ea[0]; eo[1] = ea[1]; eo[2] = ea[2];
  eo[3] = ea[3]; eo[4] = ea[4]; eo[5] = ea[5];
}

// ---- fused QKVS GEMM, fragment-order inputs: ALL loads coalesced ----------
// X in A-frag order, W in B-frag order; q pre-scaled by 1/16.
// XCD-aware remap kept (FETCH 410->34MB proven in R7).
template <int K>
__global__ __launch_bounds__(256) void gemm_qkvs(
    const unsigned short* __restrict__ X, const unsigned short* __restrict__ W,
    const float* __restrict__ bcat,
    unsigned short* __restrict__ qout, unsigned short* __restrict__ kout,
    unsigned short* __restrict__ vout, float* __restrict__ sout,
    int Nn, int nrb) {
  const int l = blockIdx.x;
  const int xcd = l & 7, j = l >> 3;
  const int q = nrb >> 3, r = nrb & 7;
  const int cnt = q + (xcd < r ? 1 : 0);
  const int lrb = j >> 4, colt = j & 15;
  if (lrb >= cnt) return;
  const int m_blk = xcd * q + min(xcd, r) + lrb;

  const int wid = threadIdx.x >> 6;
  const int lane = threadIdx.x & 63;
  const int quad = lane >> 4, lm = lane & 15;
  const int m_base = m_blk * 128 + wid * 32;
  const int n_base = colt * 64;
  const size_t abase = ((size_t)(m_blk * 4 + wid) * (K >> 5)) * 1024 + lane * 16;
  const size_t bbase = ((size_t)colt * (K >> 5)) * 2048 + lane * 32;
  f32x4 acc[2][4] = {};
#pragma unroll 4
  for (int ks = 0; ks < (K >> 5); ks++) {
    const bf16x8* ap = (const bf16x8*)(X + abase + (size_t)ks * 1024);
    const bf16x8* bp = (const bf16x8*)(W + bbase + (size_t)ks * 2048);
    bf16x8 a0 = ap[0], a1 = ap[1];
    bf16x8 b0 = bp[0], b1 = bp[1], b2 = bp[2], b3 = bp[3];
    acc[0][0] = __builtin_amdgcn_mfma_f32_16x16x32_bf16(a0, b0, acc[0][0], 0, 0, 0);
    acc[0][1] = __builtin_amdgcn_mfma_f32_16x16x32_bf16(a0, b1, acc[0][1], 0, 0, 0);
    acc[0][2] = __builtin_amdgcn_mfma_f32_16x16x32_bf16(a0, b2, acc[0][2], 0, 0, 0);
    acc[0][3] = __builtin_amdgcn_mfma_f32_16x16x32_bf16(a0, b3, acc[0][3], 0, 0, 0);
    acc[1][0] = __builtin_amdgcn_mfma_f32_16x16x32_bf16(a1, b0, acc[1][0], 0, 0, 0);
    acc[1][1] = __builtin_amdgcn_mfma_f32_16x16x32_bf16(a1, b1, acc[1][1], 0, 0, 0);
    acc[1][2] = __builtin_amdgcn_mfma_f32_16x16x32_bf16(a1, b2, acc[1][2], 0, 0, 0);
    acc[1][3] = __builtin_amdgcn_mfma_f32_16x16x32_bf16(a1, b3, acc[1][3], 0, 0, 0);
  }
#pragma unroll
  for (int mi = 0; mi < 2; mi++) {
#pragma unroll
    for (int r2 = 0; r2 < 4; r2++) {
      int row = m_base + mi * 16 + quad * 4 + r2;
      if (row >= Nn) continue;
      size_t rb = (size_t)row * 256;
#pragma unroll
      for (int ni = 0; ni < 4; ni++) {
        int col = n_base + ni * 16 + lm;
        float v = acc[mi][ni][r2] + bcat[col];
        int reg = col >> 8, c = col & 255;
        if (reg == 0)       qout[rb + c] = f2bf(v * 0.0625f);
        else if (reg == 1)  kout[rb + c] = f2bf(v);
        else if (reg == 2)  vout[rb + c] = f2bf(v);
        else                sout[rb + c] = v;
      }
    }
  }
}

// ---- node_prep: z[n] = We^T q[n] (6), c[n] = q[n].be -> zc[n][8] ----------
__global__ __launch_bounds__(256) void node_prep(
    const unsigned short* __restrict__ qv,
    const float* __restrict__ we, const float* __restrict__ be,
    float* __restrict__ zc, int Nn) {
  __shared__ float we_s[1536];
  __shared__ float be_s[256];
  for (int i = threadIdx.x; i < 1536; i += 256) we_s[i] = we[i];
  be_s[threadIdx.x] = be[threadIdx.x];
  __syncthreads();
  int wid = threadIdx.x >> 6, lane = threadIdx.x & 63;
  int n = blockIdx.x * 4 + wid;
  if (n >= Nn) return;
  int j0 = lane * 4;
  ull uq = *(const ull*)(qv + (size_t)n * 256 + j0);
  float q0 = bf2f((unsigned short)uq), q1 = bf2f((unsigned short)(uq >> 16));
  float q2 = bf2f((unsigned short)(uq >> 32)), q3 = bf2f((unsigned short)(uq >> 48));
  float part[7];
#pragma unroll
  for (int t = 0; t < 6; t++) {
    part[t] = we_s[(j0 + 0) * 6 + t] * q0 + we_s[(j0 + 1) * 6 + t] * q1
            + we_s[(j0 + 2) * 6 + t] * q2 + we_s[(j0 + 3) * 6 + t] * q3;
  }
  part[6] = be_s[j0] * q0 + be_s[j0 + 1] * q1 + be_s[j0 + 2] * q2 + be_s[j0 + 3] * q3;
#pragma unroll
  for (int off = 32; off > 0; off >>= 1) {
#pragma unroll
    for (int t = 0; t < 7; t++) part[t] += __shfl_xor(part[t], off, 64);
  }
  if (lane == 0) {
    float* zp = zc + (size_t)n * 8;
#pragma unroll
    for (int t = 0; t < 7; t++) zp[t] = part[t];
    zp[7] = 0.f;
  }
}

__device__ __forceinline__ float dot4(ull uq, ull uk) {
  return bf2f((unsigned short)uq) * bf2f((unsigned short)uk)
       + bf2f((unsigned short)(uq >> 16)) * bf2f((unsigned short)(uk >> 16))
       + bf2f((unsigned short)(uq >> 32)) * bf2f((unsigned short)(uk >> 32))
       + bf2f((unsigned short)(uq >> 48)) * bf2f((unsigned short)(uk >> 48));
}

#define SEL8_I(a, t) ((t)==0?(a)[0]:(t)==1?(a)[1]:(t)==2?(a)[2]:(t)==3?(a)[3]:(t)==4?(a)[4]:(t)==5?(a)[5]:(t)==6?(a)[6]:(a)[7])

// ---- P1: edge-parallel logits = q[dst].k[src] + z[dst].u + c[dst] ---------
__global__ __launch_bounds__(256) void edge_logits(
    const int* __restrict__ srcs, const int* __restrict__ dsts,
    const float* __restrict__ ea_perm,
    const unsigned short* __restrict__ qv, const unsigned short* __restrict__ kv,
    const float* __restrict__ zc, int E_, float* __restrict__ logits) {
  int wid = threadIdx.x >> 6, lane = threadIdx.x & 63;
  int p0 = (blockIdx.x * 4 + wid) * 8;
  if (p0 >= E_) return;
  int j0 = lane * 4;
  int s_[8], d_[8];
  if (p0 + 8 <= E_) {
    int4 sa = *(const int4*)(srcs + p0), sb = *(const int4*)(srcs + p0 + 4);
    int4 da = *(const int4*)(dsts + p0), db = *(const int4*)(dsts + p0 + 4);
    s_[0] = sa.x; s_[1] = sa.y; s_[2] = sa.z; s_[3] = sa.w;
    s_[4] = sb.x; s_[5] = sb.y; s_[6] = sb.z; s_[7] = sb.w;
    d_[0] = da.x; d_[1] = da.y; d_[2] = da.z; d_[3] = da.w;
    d_[4] = db.x; d_[5] = db.y; d_[6] = db.z; d_[7] = db.w;
  } else {
#pragma unroll
    for (int t = 0; t < 8; t++) {
      int pp = min(p0 + t, E_ - 1);
      s_[t] = srcs[pp]; d_[t] = dsts[pp];
    }
  }
  ull uk[8], uq[8];
#pragma unroll
  for (int t = 0; t < 8; t++) uk[t] = *(const ull*)(kv + (size_t)s_[t] * 256 + j0);
#pragma unroll
  for (int t = 0; t < 8; t++) uq[t] = *(const ull*)(qv + (size_t)d_[t] * 256 + j0);
  float pv[8];
#pragma unroll
  for (int t = 0; t < 8; t++) pv[t] = dot4(uq[t], uk[t]);
#pragma unroll
  for (int off = 32; off > 0; off >>= 1) {
#pragma unroll
    for (int t = 0; t < 8; t++) pv[t] += __shfl_xor(pv[t], off, 64);
  }
  // lane t (t<8) finalizes edge t: + z[dst].u + c[dst]
  if (lane < 8 && p0 + lane < E_) {
    int t = lane;
    int dd = SEL8_I(d_, t);
    float pvt = SEL8_I(pv, t);
    const float* zp = zc + (size_t)dd * 8;
    const float* u = ea_perm + (size_t)(p0 + t) * 6;
    float zd = zp[0] * u[0] + zp[1] * u[1] + zp[2] * u[2]
             + zp[3] * u[3] + zp[4] * u[4] + zp[5] * u[5] + zp[6];
    logits[p0 + t] = pvt + zd;
  }
}

// ---- P2: per-node softmax; overwrite logits with weights; also ubar -------
__global__ __launch_bounds__(256) void node_softmax(
    const int* __restrict__ row_start, const int* __restrict__ counts,
    const float* __restrict__ ea_perm,
    float* __restrict__ logits, float* __restrict__ ubar, int Nn) {
  int wid = threadIdx.x >> 6, lane = threadIdx.x & 63;
  int n = blockIdx.x * 4 + wid;
  if (n >= Nn) return;
  int beg = row_start[n], cnt = counts[n];
  if (cnt == 0) return;
  float lm = -INFINITY;
  for (int b = lane; b < cnt; b += 64) lm = fmaxf(lm, logits[beg + b]);
#pragma unroll
  for (int off = 32; off > 0; off >>= 1) lm = fmaxf(lm, __shfl_xor(lm, off, 64));
  float se = 0.f;
  for (int b = lane; b < cnt; b += 64) se += __expf(logits[beg + b] - lm);
#pragma unroll
  for (int off = 32; off > 0; off >>= 1) se += __shfl_xor(se, off, 64);
  float inv = 1.f / se;
  float u0 = 0.f, u1 = 0.f, u2 = 0.f, u3 = 0.f, u4 = 0.f, u5 = 0.f;
  for (int b = lane; b < cnt; b += 64) {
    int p = beg + b;
    float w = __expf(logits[p] - lm) * inv;
    logits[p] = w;
    const float* up = ea_perm + (size_t)p * 6;
    u0 += w * up[0]; u1 += w * up[1]; u2 += w * up[2];
    u3 += w * up[3]; u4 += w * up[4]; u5 += w * up[5];
  }
#pragma unroll
  for (int off = 32; off > 0; off >>= 1) {
    u0 += __shfl_xor(u0, off, 64); u1 += __shfl_xor(u1, off, 64);
    u2 += __shfl_xor(u2, off, 64); u3 += __shfl_xor(u3, off, 64);
    u4 += __shfl_xor(u4, off, 64); u5 += __shfl_xor(u5, off, 64);
  }
  if (lane == 0) {
    float* up = ubar + (size_t)n * 8;
    up[0] = u0; up[1] = u1; up[2] = u2; up[3] = u3; up[4] = u4; up[5] = u5;
  }
}

// ---- P3: edge-parallel SEGMENTED weighted v-sum (dsts sorted by CSR) ------
#define CHK 32
__global__ __launch_bounds__(256) void edge_seg(
    const int* __restrict__ srcs, const int* __restrict__ dsts,
    const float* __restrict__ wgt,
    const unsigned short* __restrict__ vv, int E_,
    float* __restrict__ h_acc) {
  int wid = threadIdx.x >> 6, lane = threadIdx.x & 63;
  int p0 = (blockIdx.x * 4 + wid) * CHK;
  if (p0 >= E_) return;
  int pe = min(CHK, E_ - p0);
  int j0 = lane * 4;
  int d_before = (p0 > 0) ? dsts[p0 - 1] : -1;
  int d_after  = (p0 + CHK < E_) ? dsts[p0 + CHK] : -1;
  int dd[CHK], ss[CHK];
  float w_[CHK];
  if (pe == CHK) {
#pragma unroll
    for (int t4 = 0; t4 < CHK; t4 += 4) {
      int4 dv = *(const int4*)(dsts + p0 + t4);
      int4 sv = *(const int4*)(srcs + p0 + t4);
      float4 wv = *(const float4*)(wgt + p0 + t4);
      dd[t4] = dv.x; dd[t4 + 1] = dv.y; dd[t4 + 2] = dv.z; dd[t4 + 3] = dv.w;
      ss[t4] = sv.x; ss[t4 + 1] = sv.y; ss[t4 + 2] = sv.z; ss[t4 + 3] = sv.w;
      w_[t4] = wv.x; w_[t4 + 1] = wv.y; w_[t4 + 2] = wv.z; w_[t4 + 3] = wv.w;
    }
  } else {
#pragma unroll
    for (int t = 0; t < CHK; t++) {
      int pp = min(p0 + t, E_ - 1);
      dd[t] = dsts[pp]; ss[t] = srcs[pp]; w_[t] = wgt[pp];
    }
  }
  ull uv[CHK];
#pragma unroll
  for (int t = 0; t < CHK; t++)
    uv[t] = *(const ull*)(vv + (size_t)ss[t] * 256 + j0);
  float a0 = 0.f, a1 = 0.f, a2 = 0.f, a3 = 0.f;
  int cur_d = dd[0];
#pragma unroll
  for (int t = 0; t < CHK; t++) {
    if (t >= pe) break;
    int d = dd[t];
    if (d != cur_d) {
      bool partial = (cur_d == d_before) || (cur_d == d_after);
      float* hp = h_acc + (size_t)cur_d * 256 + j0;
      if (partial) {
        atomicAdd(hp + 0, a0); atomicAdd(hp + 1, a1);
        atomicAdd(hp + 2, a2); atomicAdd(hp + 3, a3);
      } else {
        float4 o; o.x = a0; o.y = a1; o.z = a2; o.w = a3;
        *(float4*)hp = o;
      }
      a0 = a1 = a2 = a3 = 0.f;
      cur_d = d;
    }
    float ww = w_[t];
    a0 += ww * bf2f((unsigned short)uv[t]);
    a1 += ww * bf2f((unsigned short)(uv[t] >> 16));
    a2 += ww * bf2f((unsigned short)(uv[t] >> 32));
    a3 += ww * bf2f((unsigned short)(uv[t] >> 48));
  }
  {
    bool partial = (cur_d == d_before) || (cur_d == d_after);
    float* hp = h_acc + (size_t)cur_d * 256 + j0;
    if (partial) {
      atomicAdd(hp + 0, a0); atomicAdd(hp + 1, a1);
      atomicAdd(hp + 2, a2); atomicAdd(hp + 3, a3);
    } else {
      float4 o; o.x = a0; o.y = a1; o.z = a2; o.w = a3;
      *(float4*)hp = o;
    }
  }
}

// ---- P4: streaming finalize: h = relu(h_acc + We*ubar + be*[cnt>0] + skip)
// mode 0: write h bf16 to hout in A-FRAGMENT-ORDER (K=256, gemm2 input).
// mode 1: write h fp32 IN PLACE into h_acc (pool_reduce consumes).
__global__ __launch_bounds__(256) void node_finalize(
    float* __restrict__ h_acc, const float* __restrict__ ubar,
    const int* __restrict__ counts, const float* __restrict__ skipv,
    const float* __restrict__ we, const float* __restrict__ be,
    int Nn, int mode,
    unsigned short* __restrict__ hout) {
  __shared__ float we_s[1536];
  __shared__ float be_s[256];
  for (int i = threadIdx.x; i < 1536; i += 256) we_s[i] = we[i];
  be_s[threadIdx.x] = be[threadIdx.x];
  __syncthreads();
  int wid = threadIdx.x >> 6, lane = threadIdx.x & 63;
  int n = blockIdx.x * 4 + wid;
  if (n >= Nn) return;
  int j0 = lane * 4;
  float4 ha = *(const float4*)(h_acc + (size_t)n * 256 + j0);
  float4 skv = *(const float4*)(skipv + (size_t)n * 256 + j0);
  int cnt = counts[n];
  float e[4] = {0.f, 0.f, 0.f, 0.f};
  if (cnt > 0) {
    float4 u0 = *(const float4*)(ubar + (size_t)n * 8);
    float4 u1 = *(const float4*)(ubar + (size_t)n * 8 + 4);
#pragma unroll
    for (int r = 0; r < 4; r++) {
      int d = j0 + r;
      e[r] = be_s[d]
           + we_s[d * 6 + 0] * u0.x + we_s[d * 6 + 1] * u0.y + we_s[d * 6 + 2] * u0.z
           + we_s[d * 6 + 3] * u0.w + we_s[d * 6 + 4] * u1.x + we_s[d * 6 + 5] * u1.y;
    }
  }
  float h0 = fmaxf(ha.x + e[0] + skv.x, 0.f);
  float h1 = fmaxf(ha.y + e[1] + skv.y, 0.f);
  float h2 = fmaxf(ha.z + e[2] + skv.z, 0.f);
  float h3 = fmaxf(ha.w + e[3] + skv.w, 0.f);
  if (mode == 0) {
    ull hv = (ull)f2bf(h0) | ((ull)f2bf(h1) << 16) | ((ull)f2bf(h2) << 32) | ((ull)f2bf(h3) << 48);
    // A-frag-order address (K=256): cols j0..j0+3 share one 8-short unit half
    int n32 = n >> 5, lmn = n & 15, halfn = (n >> 4) & 1;
    int ks = lane >> 3, quadc = (lane >> 1) & 3, kj = (lane & 1) * 4;
    size_t a = (((size_t)n32 * 8 + ks) * 64 + quadc * 16 + lmn) * 16 + halfn * 8 + kj;
    *(ull*)(hout + a) = hv;
  } else {
    float4 o; o.x = h0; o.y = h1; o.z = h2; o.w = h3;
    *(float4*)(h_acc + (size_t)n * 256 + j0) = o;
  }
}

// ---- P5: segmented pooling over sorted batch (contiguous node ranges) -----
__global__ __launch_bounds__(256) void pool_reduce(
    const float* __restrict__ hfin, const int* __restrict__ batch, int Nn,
    float* __restrict__ gap, unsigned int* __restrict__ gmp) {
  int g = blockIdx.x, s = blockIdx.y, t = threadIdx.x;
  __shared__ int st_s, en_s;
  if (t == 0) {
    int lo = 0, hi = Nn;
    while (lo < hi) { int mid = (lo + hi) >> 1; if (batch[mid] < g) lo = mid + 1; else hi = mid; }
    st_s = lo;
    lo = 0; hi = Nn;
    while (lo < hi) { int mid = (lo + hi) >> 1; if (batch[mid] < g + 1) lo = mid + 1; else hi = mid; }
    en_s = lo;
  }
  __syncthreads();
  int st = st_s, en = en_s;
  int len = en - st;
  if (len <= 0) return;
  int nsplit = gridDim.y;
  int chunk = (len + nsplit - 1) / nsplit;
  int a = st + s * chunk;
  int b = min(a + chunk, en);
  if (a >= b) return;
  float acc = 0.f, mx = 0.f;  // h >= 0 (relu)
  for (int n = a; n < b; n++) {
    float v = hfin[(size_t)n * 256 + t];
    acc += v;
    mx = fmaxf(mx, v);
  }
  atomicAdd(&gap[(size_t)g * 256 + t], acc);
  atomicMax(&gmp[(size_t)g * 256 + t], __float_as_uint(mx));
}

// ---- per-graph pooling finalize + 3-layer MLP + sigmoid -------------------
__global__ __launch_bounds__(256) void pool_mlp(
    const float* __restrict__ gap, const unsigned int* __restrict__ gmp,
    const int* __restrict__ batch, int Nn,
    const float* __restrict__ w1, const float* __restrict__ b1,
    const float* __restrict__ w2, const float* __restrict__ b2,
    const float* __restrict__ w3, const float* __restrict__ b3,
    float* __restrict__ out) {
  int g = blockIdx.x, t = threadIdx.x;
  __shared__ float r[512];
  __shared__ float o1[256];
  __shared__ float o2[128];
  __shared__ float red[256];
  __shared__ int cnt_s;
  if (t == 0) {
    int lo = 0, hi = Nn;
    while (lo < hi) { int mid = (lo + hi) >> 1; if (batch[mid] < g) lo = mid + 1; else hi = mid; }
    int st = lo;
    lo = 0; hi = Nn;
    while (lo < hi) { int mid = (lo + hi) >> 1; if (batch[mid] < g + 1) lo = mid + 1; else hi = mid; }
    cnt_s = lo - st;
  }
  __syncthreads();
  float inv = 1.f / fmaxf((float)cnt_s, 1.f);
  r[t] = gap[(size_t)g * 256 + t] * inv;
  r[256 + t] = __uint_as_float(gmp[(size_t)g * 256 + t]);
  __syncthreads();
  {
    float a = b1[t];
    const float* wr = w1 + (size_t)t * 512;
    for (int k = 0; k < 512; k++) a += wr[k] * r[k];
    o1[t] = fmaxf(a, 0.f);
  }
  __syncthreads();
  if (t < 128) {
    float a = b2[t];
    const float* wr = w2 + (size_t)t * 256;
    for (int k = 0; k < 256; k++) a += wr[k] * o1[k];
    o2[t] = fmaxf(a, 0.f);
  }
  __syncthreads();
  red[t] = (t < 128) ? w3[t] * o2[t] : 0.f;
  __syncthreads();
  for (int s = 128; s > 0; s >>= 1) {
    if (t < s) red[t] += red[t + s];
    __syncthreads();
  }
  if (t == 0) out[g] = 1.f / (1.f + expf(-(red[0] + b3[0])));
}

// ---------------------------------------------------------------------------
extern "C" void kernel_launch(void* const* d_in, const int* in_sizes, int n_in,
                              void* d_out, int out_size, void* d_ws, size_t ws_size,
                              hipStream_t stream) {
  const int* x_idx      = (const int*)d_in[0];
  const int* edge_index = (const int*)d_in[1];
  const float* eattr    = (const float*)d_in[2];
  const int* batch      = (const int*)d_in[3];
  const float* emb      = (const float*)d_in[4];
  const float* c1_wq = (const float*)d_in[5],  *c1_bq = (const float*)d_in[6];
  const float* c1_wk = (const float*)d_in[7],  *c1_bk = (const float*)d_in[8];
  const float* c1_wv = (const float*)d_in[9],  *c1_bv = (const float*)d_in[10];
  const float* c1_we = (const float*)d_in[11], *c1_be = (const float*)d_in[12];
  const float* c1_ws = (const float*)d_in[13], *c1_bs = (const float*)d_in[14];
  const float* c2_wq = (const float*)d_in[15], *c2_bq = (const float*)d_in[16];
  const float* c2_wk = (const float*)d_in[17], *c2_bk = (const float*)d_in[18];
  const float* c2_wv = (const float*)d_in[19], *c2_bv = (const float*)d_in[20];
  const float* c2_we = (const float*)d_in[21], *c2_be = (const float*)d_in[22];
  const float* c2_ws = (const float*)d_in[23], *c2_bs = (const float*)d_in[24];
  const float* w1 = (const float*)d_in[25], *b1 = (const float*)d_in[26];
  const float* w2 = (const float*)d_in[27], *b2 = (const float*)d_in[28];
  const float* w3 = (const float*)d_in[29], *b3 = (const float*)d_in[30];

  const int Nn = in_sizes[3];        // 50000
  const int Ee = in_sizes[1] / 2;    // 300000
  const int nrb = (Nn + 127) / 128;  // 391 row-blocks (gemm grid + padding)

  char* ws = (char*)d_ws;
  size_t off = 0;
  auto alloc = [&](size_t bytes) -> void* {
    void* p = ws + off;
    off += (bytes + 255) & ~(size_t)255;
    return p;
  };
  // xbf/h1bf padded to whole 128-row blocks (frag-order reads go to nrb*128)
  unsigned short* xbf   = (unsigned short*)alloc((size_t)nrb * 128 * 512 * 2);
  unsigned short* qbf   = (unsigned short*)alloc((size_t)Nn * 256 * 2);
  unsigned short* kbf   = (unsigned short*)alloc((size_t)Nn * 256 * 2);
  unsigned short* vbf   = (unsigned short*)alloc((size_t)Nn * 256 * 2);
  float*          skipf = (float*)alloc((size_t)Nn * 256 * 4);
  unsigned short* h1bf  = (unsigned short*)alloc((size_t)nrb * 128 * 256 * 2);
  unsigned short* Wcat1 = (unsigned short*)alloc((size_t)1024 * 512 * 2);
  float*          bcat1 = (float*)alloc(1024 * 4);
  unsigned short* Wcat2 = (unsigned short*)alloc((size_t)1024 * 256 * 2);
  float*          bcat2 = (float*)alloc(1024 * 4);
  int*            counts    = (int*)alloc((size_t)Nn * 4);
  int*            row_start = (int*)alloc((size_t)Nn * 4);
  int*            cursor    = (int*)alloc((size_t)Nn * 4);
  int*            srcs      = (int*)alloc((size_t)Ee * 4);
  int*            dsts      = (int*)alloc((size_t)Ee * 4);
  float*          ea_perm   = (float*)alloc((size_t)Ee * 6 * 4);
  float*          logits    = (float*)alloc((size_t)Ee * 4);   // becomes weights
  float*          zc        = (float*)alloc((size_t)Nn * 8 * 4);
  float*          ubar      = (float*)alloc((size_t)Nn * 8 * 4);
  int*            total     = (int*)alloc(256);
  float*          gap       = (float*)alloc((size_t)64 * 256 * 4);
  unsigned int*   gmp       = (unsigned int*)alloc((size_t)64 * 256 * 4);
  // h_acc (50k x 256 fp32 = 51.2 MB) ALIASES xbf (51.25 MB padded): xbf is
  // dead after gemm1; h_acc first touched after it. ~221 MB total.
  float* h_acc = (float*)xbf;

  const int* srcA = edge_index;
  const int* dstA = edge_index + Ee;

  hipMemsetAsync(counts, 0, (size_t)Nn * 4, stream);
  hipMemsetAsync(total, 0, 4, stream);
  hipMemsetAsync(gap, 0, (size_t)64 * 256 * 4, stream);
  hipMemsetAsync(gmp, 0, (size_t)64 * 256 * 4, stream);

  pack_weights<<<(1024 * 512 + 255) / 256, 256, 0, stream>>>(
      c1_wq, c1_wk, c1_wv, c1_ws, c1_bq, c1_bk, c1_bv, c1_bs, Wcat1, bcat1, 9);
  pack_weights<<<(1024 * 256 + 255) / 256, 256, 0, stream>>>(
      c2_wq, c2_wk, c2_wv, c2_ws, c2_bq, c2_bk, c2_bv, c2_bs, Wcat2, bcat2, 8);
  embed_gather<<<((Nn * 512) + 255) / 256, 256, 0, stream>>>(x_idx, emb, xbf, Nn * 512);
  count_dst<<<(Ee + 255) / 256, 256, 0, stream>>>(dstA, counts, Ee);
  alloc_rows<<<(Nn + 255) / 256, 256, 0, stream>>>(counts, row_start, cursor, total, Nn);
  scatter_edges<<<(Ee + 255) / 256, 256, 0, stream>>>(dstA, srcA, eattr, cursor,
                                                      srcs, dsts, ea_perm, Ee);

  // XCD-aware gemm grid: 8 XCD groups x max-row-blocks-per-XCD x 16 col-tiles
  const int rbmax = nrb / 8 + ((nrb % 8) ? 1 : 0);
  const int ggrid = 8 * rbmax * 16;
  const int egrid = (Ee + 31) / 32;
  const int sgrid = (Ee + CHK * 4 - 1) / (CHK * 4);
  const int ngrid = (Nn + 3) / 4;

  // layer 1
  gemm_qkvs<512><<<ggrid, 256, 0, stream>>>(xbf, Wcat1, bcat1, qbf, kbf, vbf,
                                            skipf, Nn, nrb);
  node_prep<<<ngrid, 256, 0, stream>>>(qbf, c1_we, c1_be, zc, Nn);
  edge_logits<<<egrid, 256, 0, stream>>>(srcs, dsts, ea_perm, qbf, kbf, zc, Ee, logits);
  node_softmax<<<ngrid, 256, 0, stream>>>(row_start, counts, ea_perm, logits, ubar, Nn);
  hipMemsetAsync(h_acc, 0, (size_t)Nn * 256 * 4, stream);   // xbf dead now
  edge_seg<<<sgrid, 256, 0, stream>>>(srcs, dsts, logits, vbf, Ee, h_acc);
  node_finalize<<<ngrid, 256, 0, stream>>>(h_acc, ubar, counts, skipf,
                                           c1_we, c1_be, Nn, 0, h1bf);

  // layer 2
  gemm_qkvs<256><<<ggrid, 256, 0, stream>>>(h1bf, Wcat2, bcat2, qbf, kbf, vbf,
                                            skipf, Nn, nrb);
  node_prep<<<ngrid, 256, 0, stream>>>(qbf, c2_we, c2_be, zc, Nn);
  edge_logits<<<egrid, 256, 0, stream>>>(srcs, dsts, ea_perm, qbf, kbf, zc, Ee, logits);
  node_softmax<<<ngrid, 256, 0, stream>>>(row_start, counts, ea_perm, logits, ubar, Nn);
  hipMemsetAsync(h_acc, 0, (size_t)Nn * 256 * 4, stream);
  edge_seg<<<sgrid, 256, 0, stream>>>(srcs, dsts, logits, vbf, Ee, h_acc);
  node_finalize<<<ngrid, 256, 0, stream>>>(h_acc, ubar, counts, skipf,
                                           c2_we, c2_be, Nn, 1, nullptr);

  // segmented pooling (batch sorted -> contiguous ranges), then MLP
  dim3 pg(64, 16);
  pool_reduce<<<pg, 256, 0, stream>>>(h_acc, batch, Nn, gap, gmp);
  pool_mlp<<<64, 256, 0, stream>>>(gap, gmp, batch, Nn, w1, b1, w2, b2, w3, b3,
                                   (float*)d_out);
}

// Round 10
// 986.510 us; speedup vs baseline: 1.2598x; 1.0328x over previous
//
#include <hip/hip_runtime.h>

typedef unsigned long long ull;
typedef __bf16 bf16x8 __attribute__((ext_vector_type(8)));
typedef float f32x4 __attribute__((ext_vector_type(4)));

__device__ __forceinline__ float bf2f(unsigned short u) {
  union { unsigned int i; float f; } c; c.i = ((unsigned int)u) << 16; return c.f;
}
__device__ __forceinline__ unsigned short f2bf(float f) {
  union { float f; unsigned int i; } c; c.f = f;
  unsigned int u = c.i;
  u += 0x7fffu + ((u >> 16) & 1u);
  return (unsigned short)(u >> 16);
}

// ---- pack 4x [256,K] fp32 weights -> bf16 B-FRAGMENT-ORDER + bias concat --
// Layout: Wcat[colt][ks][rg][lane][kj]  (fragment index OUTSIDE lane, so
// each 16B load instruction in gemm is lane-contiguous: 64x16B = 1KB burst).
//   element = W[colt*64 + rg*16 + lm][ks*32 + quad*8 + kj], lane=quad*16+lm
__global__ __launch_bounds__(256) void pack_weights(
    const float* __restrict__ wq, const float* __restrict__ wk,
    const float* __restrict__ wv, const float* __restrict__ ws,
    const float* __restrict__ bq, const float* __restrict__ bk,
    const float* __restrict__ bv, const float* __restrict__ bs,
    unsigned short* __restrict__ Wcat, float* __restrict__ bcat, int logK) {
  int idx = blockIdx.x * 256 + threadIdx.x;
  if (idx < 1024) {
    int rr = idx >> 8, cc = idx & 255;
    const float* bp = (rr == 0) ? bq : (rr == 1) ? bk : (rr == 2) ? bv : bs;
    bcat[idx] = bp[cc];
  }
  int K = 1 << logK;
  if (idx >= (1024 << logK)) return;
  int kj = idx & 7;
  int lane = (idx >> 3) & 63;
  int rg = (idx >> 9) & 3;
  int ksbits = logK - 5;
  int ks = (idx >> 11) & ((1 << ksbits) - 1);
  int colt = idx >> (11 + ksbits);
  int quad = lane >> 4, lm = lane & 15;
  int o = colt * 64 + rg * 16 + lm;
  int k = ks * 32 + quad * 8 + kj;
  int rr = o >> 8, oo = o & 255;
  const float* wp = (rr == 0) ? wq : (rr == 1) ? wk : (rr == 2) ? wv : ws;
  Wcat[idx] = f2bf(wp[oo * K + k]);
}

// ---- embedding gather -> A-FRAGMENT-ORDER xbf (K=512) ---------------------
// Layout: xbf[n32][ks][half][lane][kj]: each of a0 (half=0) / a1 (half=1) is
// a lane-contiguous 1KB burst in gemm.
//   element (n,d): n32=n>>5, half=(n>>4)&1, lm=n&15; ks=d>>5, quad=(d>>3)&3, kj=d&7
__global__ __launch_bounds__(256) void embed_gather(
    const int* __restrict__ x_idx, const float* __restrict__ emb,
    unsigned short* __restrict__ xbf, int total) {
  int idx = blockIdx.x * 256 + threadIdx.x;
  if (idx >= total) return;
  int n = idx >> 9, d = idx & 511, f = d >> 6, j = d & 63;
  int vi = x_idx[n * 8 + f];
  int n32 = n >> 5, lm = n & 15, half = (n >> 4) & 1;
  int ks = d >> 5, quad = (d >> 3) & 3, kj = d & 7;
  size_t a = (((size_t)(n32 * 16 + ks)) * 2 + half) * 512 + (quad * 16 + lm) * 8 + kj;
  xbf[a] = f2bf(emb[vi * 64 + j]);
}

// ---- CSR build ------------------------------------------------------------
__global__ __launch_bounds__(256) void count_dst(const int* __restrict__ dst,
                                                 int* __restrict__ counts, int E_) {
  int i = blockIdx.x * 256 + threadIdx.x;
  if (i < E_) atomicAdd(&counts[dst[i]], 1);
}

__global__ __launch_bounds__(256) void alloc_rows(const int* __restrict__ counts,
                                                  int* __restrict__ row_start,
                                                  int* __restrict__ cursor,
                                                  int* __restrict__ total, int n) {
  int i = blockIdx.x * 256 + threadIdx.x;
  int lane = threadIdx.x & 63;
  int c = (i < n) ? counts[i] : 0;
  int incl = c;
#pragma unroll
  for (int off = 1; off < 64; off <<= 1) {
    int t = __shfl_up(incl, off, 64);
    if (lane >= off) incl += t;
  }
  int base = 0;
  if (lane == 63) base = atomicAdd(total, incl);
  base = __shfl(base, 63, 64);
  int st = base + incl - c;
  if (i < n) { row_start[i] = st; cursor[i] = st; }
}

// scatter edges into CSR order; materialize permuted src/dst ids and attrs
__global__ __launch_bounds__(256) void scatter_edges(
    const int* __restrict__ dst, const int* __restrict__ srcA,
    const float* __restrict__ eattr, int* __restrict__ cursor,
    int* __restrict__ srcs, int* __restrict__ dsts,
    float* __restrict__ ea_perm, int E_) {
  int i = blockIdx.x * 256 + threadIdx.x;
  if (i >= E_) return;
  int d = dst[i];
  int p = atomicAdd(&cursor[d], 1);
  srcs[p] = srcA[i];
  dsts[p] = d;
  const float* ea = eattr + (size_t)i * 6;
  float* eo = ea_perm + (size_t)p * 6;
  eo[0] = ea[0]; eo[1] = ea[1]; eo[2] = ea[2];
  eo[3] = ea[3]; eo[4] = ea[4]; eo[5] = ea[5];
}

// ---- fused QKVS GEMM, fully-coalesced fragment-order inputs ---------------
// Every A/B load instruction is a lane-contiguous 1KB burst (16 full lines),
// vs R9's 32-64 sparse lines per instruction. XCD remap kept.
template <int K>
__global__ __launch_bounds__(256) void gemm_qkvs(
    const unsigned short* __restrict__ X, const unsigned short* __restrict__ W,
    const float* __restrict__ bcat,
    unsigned short* __restrict__ qout, unsigned short* __restrict__ kout,
    unsigned short* __restrict__ vout, float* __restrict__ sout,
    int Nn, int nrb) {
  const int l = blockIdx.x;
  const int xcd = l & 7, j = l >> 3;
  const int q = nrb >> 3, r = nrb & 7;
  const int cnt = q + (xcd < r ? 1 : 0);
  const int lrb = j >> 4, colt = j & 15;
  if (lrb >= cnt) return;
  const int m_blk = xcd * q + min(xcd, r) + lrb;

  const int wid = threadIdx.x >> 6;
  const int lane = threadIdx.x & 63;
  const int quad = lane >> 4, lm = lane & 15;
  const int m_base = m_blk * 128 + wid * 32;
  const int n_base = colt * 64;
  const size_t abase = (size_t)(m_blk * 4 + wid) * (K >> 5) * 1024 + lane * 8;
  const size_t bbase = (size_t)colt * (K >> 5) * 2048 + lane * 8;
  f32x4 acc[2][4] = {};
#pragma unroll 4
  for (int ks = 0; ks < (K >> 5); ks++) {
    const unsigned short* ap = X + abase + (size_t)ks * 1024;
    const unsigned short* bp = W + bbase + (size_t)ks * 2048;
    bf16x8 a0 = *(const bf16x8*)(ap);
    bf16x8 a1 = *(const bf16x8*)(ap + 512);
    bf16x8 b0 = *(const bf16x8*)(bp);
    bf16x8 b1 = *(const bf16x8*)(bp + 512);
    bf16x8 b2 = *(const bf16x8*)(bp + 1024);
    bf16x8 b3 = *(const bf16x8*)(bp + 1536);
    acc[0][0] = __builtin_amdgcn_mfma_f32_16x16x32_bf16(a0, b0, acc[0][0], 0, 0, 0);
    acc[0][1] = __builtin_amdgcn_mfma_f32_16x16x32_bf16(a0, b1, acc[0][1], 0, 0, 0);
    acc[0][2] = __builtin_amdgcn_mfma_f32_16x16x32_bf16(a0, b2, acc[0][2], 0, 0, 0);
    acc[0][3] = __builtin_amdgcn_mfma_f32_16x16x32_bf16(a0, b3, acc[0][3], 0, 0, 0);
    acc[1][0] = __builtin_amdgcn_mfma_f32_16x16x32_bf16(a1, b0, acc[1][0], 0, 0, 0);
    acc[1][1] = __builtin_amdgcn_mfma_f32_16x16x32_bf16(a1, b1, acc[1][1], 0, 0, 0);
    acc[1][2] = __builtin_amdgcn_mfma_f32_16x16x32_bf16(a1, b2, acc[1][2], 0, 0, 0);
    acc[1][3] = __builtin_amdgcn_mfma_f32_16x16x32_bf16(a1, b3, acc[1][3], 0, 0, 0);
  }
#pragma unroll
  for (int mi = 0; mi < 2; mi++) {
#pragma unroll
    for (int r2 = 0; r2 < 4; r2++) {
      int row = m_base + mi * 16 + quad * 4 + r2;
      if (row >= Nn) continue;
      size_t rb = (size_t)row * 256;
#pragma unroll
      for (int ni = 0; ni < 4; ni++) {
        int col = n_base + ni * 16 + lm;
        float v = acc[mi][ni][r2] + bcat[col];
        int reg = col >> 8, c = col & 255;
        if (reg == 0)       qout[rb + c] = f2bf(v * 0.0625f);
        else if (reg == 1)  kout[rb + c] = f2bf(v);
        else if (reg == 2)  vout[rb + c] = f2bf(v);
        else                sout[rb + c] = v;
      }
    }
  }
}

// ---- node_prep: z[n] = We^T q[n] (6), c[n] = q[n].be -> zc[n][8] ----------
__global__ __launch_bounds__(256) void node_prep(
    const unsigned short* __restrict__ qv,
    const float* __restrict__ we, const float* __restrict__ be,
    float* __restrict__ zc, int Nn) {
  __shared__ float we_s[1536];
  __shared__ float be_s[256];
  for (int i = threadIdx.x; i < 1536; i += 256) we_s[i] = we[i];
  be_s[threadIdx.x] = be[threadIdx.x];
  __syncthreads();
  int wid = threadIdx.x >> 6, lane = threadIdx.x & 63;
  int n = blockIdx.x * 4 + wid;
  if (n >= Nn) return;
  int j0 = lane * 4;
  ull uq = *(const ull*)(qv + (size_t)n * 256 + j0);
  float q0 = bf2f((unsigned short)uq), q1 = bf2f((unsigned short)(uq >> 16));
  float q2 = bf2f((unsigned short)(uq >> 32)), q3 = bf2f((unsigned short)(uq >> 48));
  float part[7];
#pragma unroll
  for (int t = 0; t < 6; t++) {
    part[t] = we_s[(j0 + 0) * 6 + t] * q0 + we_s[(j0 + 1) * 6 + t] * q1
            + we_s[(j0 + 2) * 6 + t] * q2 + we_s[(j0 + 3) * 6 + t] * q3;
  }
  part[6] = be_s[j0] * q0 + be_s[j0 + 1] * q1 + be_s[j0 + 2] * q2 + be_s[j0 + 3] * q3;
#pragma unroll
  for (int off = 32; off > 0; off >>= 1) {
#pragma unroll
    for (int t = 0; t < 7; t++) part[t] += __shfl_xor(part[t], off, 64);
  }
  if (lane == 0) {
    float* zp = zc + (size_t)n * 8;
#pragma unroll
    for (int t = 0; t < 7; t++) zp[t] = part[t];
    zp[7] = 0.f;
  }
}

__device__ __forceinline__ float dot4(ull uq, ull uk) {
  return bf2f((unsigned short)uq) * bf2f((unsigned short)uk)
       + bf2f((unsigned short)(uq >> 16)) * bf2f((unsigned short)(uk >> 16))
       + bf2f((unsigned short)(uq >> 32)) * bf2f((unsigned short)(uk >> 32))
       + bf2f((unsigned short)(uq >> 48)) * bf2f((unsigned short)(uk >> 48));
}

#define SEL8_I(a, t) ((t)==0?(a)[0]:(t)==1?(a)[1]:(t)==2?(a)[2]:(t)==3?(a)[3]:(t)==4?(a)[4]:(t)==5?(a)[5]:(t)==6?(a)[6]:(a)[7])

// ---- P1: edge-parallel logits = q[dst].k[src] + z[dst].u + c[dst] ---------
__global__ __launch_bounds__(256) void edge_logits(
    const int* __restrict__ srcs, const int* __restrict__ dsts,
    const float* __restrict__ ea_perm,
    const unsigned short* __restrict__ qv, const unsigned short* __restrict__ kv,
    const float* __restrict__ zc, int E_, float* __restrict__ logits) {
  int wid = threadIdx.x >> 6, lane = threadIdx.x & 63;
  int p0 = (blockIdx.x * 4 + wid) * 8;
  if (p0 >= E_) return;
  int j0 = lane * 4;
  int s_[8], d_[8];
  if (p0 + 8 <= E_) {
    int4 sa = *(const int4*)(srcs + p0), sb = *(const int4*)(srcs + p0 + 4);
    int4 da = *(const int4*)(dsts + p0), db = *(const int4*)(dsts + p0 + 4);
    s_[0] = sa.x; s_[1] = sa.y; s_[2] = sa.z; s_[3] = sa.w;
    s_[4] = sb.x; s_[5] = sb.y; s_[6] = sb.z; s_[7] = sb.w;
    d_[0] = da.x; d_[1] = da.y; d_[2] = da.z; d_[3] = da.w;
    d_[4] = db.x; d_[5] = db.y; d_[6] = db.z; d_[7] = db.w;
  } else {
#pragma unroll
    for (int t = 0; t < 8; t++) {
      int pp = min(p0 + t, E_ - 1);
      s_[t] = srcs[pp]; d_[t] = dsts[pp];
    }
  }
  ull uk[8], uq[8];
#pragma unroll
  for (int t = 0; t < 8; t++) uk[t] = *(const ull*)(kv + (size_t)s_[t] * 256 + j0);
#pragma unroll
  for (int t = 0; t < 8; t++) uq[t] = *(const ull*)(qv + (size_t)d_[t] * 256 + j0);
  float pv[8];
#pragma unroll
  for (int t = 0; t < 8; t++) pv[t] = dot4(uq[t], uk[t]);
#pragma unroll
  for (int off = 32; off > 0; off >>= 1) {
#pragma unroll
    for (int t = 0; t < 8; t++) pv[t] += __shfl_xor(pv[t], off, 64);
  }
  // lane t (t<8) finalizes edge t: + z[dst].u + c[dst]
  if (lane < 8 && p0 + lane < E_) {
    int t = lane;
    int dd = SEL8_I(d_, t);
    float pvt = SEL8_I(pv, t);
    const float* zp = zc + (size_t)dd * 8;
    const float* u = ea_perm + (size_t)(p0 + t) * 6;
    float zd = zp[0] * u[0] + zp[1] * u[1] + zp[2] * u[2]
             + zp[3] * u[3] + zp[4] * u[4] + zp[5] * u[5] + zp[6];
    logits[p0 + t] = pvt + zd;
  }
}

// ---- P2: per-node softmax; overwrite logits with weights; also ubar -------
__global__ __launch_bounds__(256) void node_softmax(
    const int* __restrict__ row_start, const int* __restrict__ counts,
    const float* __restrict__ ea_perm,
    float* __restrict__ logits, float* __restrict__ ubar, int Nn) {
  int wid = threadIdx.x >> 6, lane = threadIdx.x & 63;
  int n = blockIdx.x * 4 + wid;
  if (n >= Nn) return;
  int beg = row_start[n], cnt = counts[n];
  if (cnt == 0) return;
  float lm = -INFINITY;
  for (int b = lane; b < cnt; b += 64) lm = fmaxf(lm, logits[beg + b]);
#pragma unroll
  for (int off = 32; off > 0; off >>= 1) lm = fmaxf(lm, __shfl_xor(lm, off, 64));
  float se = 0.f;
  for (int b = lane; b < cnt; b += 64) se += __expf(logits[beg + b] - lm);
#pragma unroll
  for (int off = 32; off > 0; off >>= 1) se += __shfl_xor(se, off, 64);
  float inv = 1.f / se;
  float u0 = 0.f, u1 = 0.f, u2 = 0.f, u3 = 0.f, u4 = 0.f, u5 = 0.f;
  for (int b = lane; b < cnt; b += 64) {
    int p = beg + b;
    float w = __expf(logits[p] - lm) * inv;
    logits[p] = w;
    const float* up = ea_perm + (size_t)p * 6;
    u0 += w * up[0]; u1 += w * up[1]; u2 += w * up[2];
    u3 += w * up[3]; u4 += w * up[4]; u5 += w * up[5];
  }
#pragma unroll
  for (int off = 32; off > 0; off >>= 1) {
    u0 += __shfl_xor(u0, off, 64); u1 += __shfl_xor(u1, off, 64);
    u2 += __shfl_xor(u2, off, 64); u3 += __shfl_xor(u3, off, 64);
    u4 += __shfl_xor(u4, off, 64); u5 += __shfl_xor(u5, off, 64);
  }
  if (lane == 0) {
    float* up = ubar + (size_t)n * 8;
    up[0] = u0; up[1] = u1; up[2] = u2; up[3] = u3; up[4] = u4; up[5] = u5;
  }
}

// ---- P3: edge-parallel SEGMENTED weighted v-sum (dsts sorted by CSR) ------
#define CHK 32
__global__ __launch_bounds__(256) void edge_seg(
    const int* __restrict__ srcs, const int* __restrict__ dsts,
    const float* __restrict__ wgt,
    const unsigned short* __restrict__ vv, int E_,
    float* __restrict__ h_acc) {
  int wid = threadIdx.x >> 6, lane = threadIdx.x & 63;
  int p0 = (blockIdx.x * 4 + wid) * CHK;
  if (p0 >= E_) return;
  int pe = min(CHK, E_ - p0);
  int j0 = lane * 4;
  int d_before = (p0 > 0) ? dsts[p0 - 1] : -1;
  int d_after  = (p0 + CHK < E_) ? dsts[p0 + CHK] : -1;
  int dd[CHK], ss[CHK];
  float w_[CHK];
  if (pe == CHK) {
#pragma unroll
    for (int t4 = 0; t4 < CHK; t4 += 4) {
      int4 dv = *(const int4*)(dsts + p0 + t4);
      int4 sv = *(const int4*)(srcs + p0 + t4);
      float4 wv = *(const float4*)(wgt + p0 + t4);
      dd[t4] = dv.x; dd[t4 + 1] = dv.y; dd[t4 + 2] = dv.z; dd[t4 + 3] = dv.w;
      ss[t4] = sv.x; ss[t4 + 1] = sv.y; ss[t4 + 2] = sv.z; ss[t4 + 3] = sv.w;
      w_[t4] = wv.x; w_[t4 + 1] = wv.y; w_[t4 + 2] = wv.z; w_[t4 + 3] = wv.w;
    }
  } else {
#pragma unroll
    for (int t = 0; t < CHK; t++) {
      int pp = min(p0 + t, E_ - 1);
      dd[t] = dsts[pp]; ss[t] = srcs[pp]; w_[t] = wgt[pp];
    }
  }
  ull uv[CHK];
#pragma unroll
  for (int t = 0; t < CHK; t++)
    uv[t] = *(const ull*)(vv + (size_t)ss[t] * 256 + j0);
  float a0 = 0.f, a1 = 0.f, a2 = 0.f, a3 = 0.f;
  int cur_d = dd[0];
#pragma unroll
  for (int t = 0; t < CHK; t++) {
    if (t >= pe) break;
    int d = dd[t];
    if (d != cur_d) {
      bool partial = (cur_d == d_before) || (cur_d == d_after);
      float* hp = h_acc + (size_t)cur_d * 256 + j0;
      if (partial) {
        atomicAdd(hp + 0, a0); atomicAdd(hp + 1, a1);
        atomicAdd(hp + 2, a2); atomicAdd(hp + 3, a3);
      } else {
        float4 o; o.x = a0; o.y = a1; o.z = a2; o.w = a3;
        *(float4*)hp = o;
      }
      a0 = a1 = a2 = a3 = 0.f;
      cur_d = d;
    }
    float ww = w_[t];
    a0 += ww * bf2f((unsigned short)uv[t]);
    a1 += ww * bf2f((unsigned short)(uv[t] >> 16));
    a2 += ww * bf2f((unsigned short)(uv[t] >> 32));
    a3 += ww * bf2f((unsigned short)(uv[t] >> 48));
  }
  {
    bool partial = (cur_d == d_before) || (cur_d == d_after);
    float* hp = h_acc + (size_t)cur_d * 256 + j0;
    if (partial) {
      atomicAdd(hp + 0, a0); atomicAdd(hp + 1, a1);
      atomicAdd(hp + 2, a2); atomicAdd(hp + 3, a3);
    } else {
      float4 o; o.x = a0; o.y = a1; o.z = a2; o.w = a3;
      *(float4*)hp = o;
    }
  }
}

// ---- P4: streaming finalize: h = relu(h_acc + We*ubar + be*[cnt>0] + skip)
// mode 0: write h bf16 to hout in A-FRAGMENT-ORDER (K=256, gemm2 input).
// mode 1: write h fp32 IN PLACE into h_acc (pool_reduce consumes).
__global__ __launch_bounds__(256) void node_finalize(
    float* __restrict__ h_acc, const float* __restrict__ ubar,
    const int* __restrict__ counts, const float* __restrict__ skipv,
    const float* __restrict__ we, const float* __restrict__ be,
    int Nn, int mode,
    unsigned short* __restrict__ hout) {
  __shared__ float we_s[1536];
  __shared__ float be_s[256];
  for (int i = threadIdx.x; i < 1536; i += 256) we_s[i] = we[i];
  be_s[threadIdx.x] = be[threadIdx.x];
  __syncthreads();
  int wid = threadIdx.x >> 6, lane = threadIdx.x & 63;
  int n = blockIdx.x * 4 + wid;
  if (n >= Nn) return;
  int j0 = lane * 4;
  float4 ha = *(const float4*)(h_acc + (size_t)n * 256 + j0);
  float4 skv = *(const float4*)(skipv + (size_t)n * 256 + j0);
  int cnt = counts[n];
  float e[4] = {0.f, 0.f, 0.f, 0.f};
  if (cnt > 0) {
    float4 u0 = *(const float4*)(ubar + (size_t)n * 8);
    float4 u1 = *(const float4*)(ubar + (size_t)n * 8 + 4);
#pragma unroll
    for (int r = 0; r < 4; r++) {
      int d = j0 + r;
      e[r] = be_s[d]
           + we_s[d * 6 + 0] * u0.x + we_s[d * 6 + 1] * u0.y + we_s[d * 6 + 2] * u0.z
           + we_s[d * 6 + 3] * u0.w + we_s[d * 6 + 4] * u1.x + we_s[d * 6 + 5] * u1.y;
    }
  }
  float h0 = fmaxf(ha.x + e[0] + skv.x, 0.f);
  float h1 = fmaxf(ha.y + e[1] + skv.y, 0.f);
  float h2 = fmaxf(ha.z + e[2] + skv.z, 0.f);
  float h3 = fmaxf(ha.w + e[3] + skv.w, 0.f);
  if (mode == 0) {
    ull hv = (ull)f2bf(h0) | ((ull)f2bf(h1) << 16) | ((ull)f2bf(h2) << 32) | ((ull)f2bf(h3) << 48);
    // A-frag-order address (K=256): d = lane*4 -> ks=lane>>3, quad=(lane>>1)&3,
    // kj=(lane&1)*4; layout [n32][ks][half][lane'][kj]
    int n32 = n >> 5, lmn = n & 15, halfn = (n >> 4) & 1;
    int ks = lane >> 3, quadc = (lane >> 1) & 3, kjc = (lane & 1) * 4;
    size_t a = (((size_t)(n32 * 8 + ks)) * 2 + halfn) * 512 + (quadc * 16 + lmn) * 8 + kjc;
    *(ull*)(hout + a) = hv;
  } else {
    float4 o; o.x = h0; o.y = h1; o.z = h2; o.w = h3;
    *(float4*)(h_acc + (size_t)n * 256 + j0) = o;
  }
}

// ---- P5: segmented pooling over sorted batch (contiguous node ranges) -----
__global__ __launch_bounds__(256) void pool_reduce(
    const float* __restrict__ hfin, const int* __restrict__ batch, int Nn,
    float* __restrict__ gap, unsigned int* __restrict__ gmp) {
  int g = blockIdx.x, s = blockIdx.y, t = threadIdx.x;
  __shared__ int st_s, en_s;
  if (t == 0) {
    int lo = 0, hi = Nn;
    while (lo < hi) { int mid = (lo + hi) >> 1; if (batch[mid] < g) lo = mid + 1; else hi = mid; }
    st_s = lo;
    lo = 0; hi = Nn;
    while (lo < hi) { int mid = (lo + hi) >> 1; if (batch[mid] < g + 1) lo = mid + 1; else hi = mid; }
    en_s = lo;
  }
  __syncthreads();
  int st = st_s, en = en_s;
  int len = en - st;
  if (len <= 0) return;
  int nsplit = gridDim.y;
  int chunk = (len + nsplit - 1) / nsplit;
  int a = st + s * chunk;
  int b = min(a + chunk, en);
  if (a >= b) return;
  float acc = 0.f, mx = 0.f;  // h >= 0 (relu)
  for (int n = a; n < b; n++) {
    float v = hfin[(size_t)n * 256 + t];
    acc += v;
    mx = fmaxf(mx, v);
  }
  atomicAdd(&gap[(size_t)g * 256 + t], acc);
  atomicMax(&gmp[(size_t)g * 256 + t], __float_as_uint(mx));
}

// ---- per-graph pooling finalize + 3-layer MLP + sigmoid -------------------
__global__ __launch_bounds__(256) void pool_mlp(
    const float* __restrict__ gap, const unsigned int* __restrict__ gmp,
    const int* __restrict__ batch, int Nn,
    const float* __restrict__ w1, const float* __restrict__ b1,
    const float* __restrict__ w2, const float* __restrict__ b2,
    const float* __restrict__ w3, const float* __restrict__ b3,
    float* __restrict__ out) {
  int g = blockIdx.x, t = threadIdx.x;
  __shared__ float r[512];
  __shared__ float o1[256];
  __shared__ float o2[128];
  __shared__ float red[256];
  __shared__ int cnt_s;
  if (t == 0) {
    int lo = 0, hi = Nn;
    while (lo < hi) { int mid = (lo + hi) >> 1; if (batch[mid] < g) lo = mid + 1; else hi = mid; }
    int st = lo;
    lo = 0; hi = Nn;
    while (lo < hi) { int mid = (lo + hi) >> 1; if (batch[mid] < g + 1) lo = mid + 1; else hi = mid; }
    cnt_s = lo - st;
  }
  __syncthreads();
  float inv = 1.f / fmaxf((float)cnt_s, 1.f);
  r[t] = gap[(size_t)g * 256 + t] * inv;
  r[256 + t] = __uint_as_float(gmp[(size_t)g * 256 + t]);
  __syncthreads();
  {
    float a = b1[t];
    const float* wr = w1 + (size_t)t * 512;
    for (int k = 0; k < 512; k++) a += wr[k] * r[k];
    o1[t] = fmaxf(a, 0.f);
  }
  __syncthreads();
  if (t < 128) {
    float a = b2[t];
    const float* wr = w2 + (size_t)t * 256;
    for (int k = 0; k < 256; k++) a += wr[k] * o1[k];
    o2[t] = fmaxf(a, 0.f);
  }
  __syncthreads();
  red[t] = (t < 128) ? w3[t] * o2[t] : 0.f;
  __syncthreads();
  for (int s = 128; s > 0; s >>= 1) {
    if (t < s) red[t] += red[t + s];
    __syncthreads();
  }
  if (t == 0) out[g] = 1.f / (1.f + expf(-(red[0] + b3[0])));
}

// ---------------------------------------------------------------------------
extern "C" void kernel_launch(void* const* d_in, const int* in_sizes, int n_in,
                              void* d_out, int out_size, void* d_ws, size_t ws_size,
                              hipStream_t stream) {
  const int* x_idx      = (const int*)d_in[0];
  const int* edge_index = (const int*)d_in[1];
  const float* eattr    = (const float*)d_in[2];
  const int* batch      = (const int*)d_in[3];
  const float* emb      = (const float*)d_in[4];
  const float* c1_wq = (const float*)d_in[5],  *c1_bq = (const float*)d_in[6];
  const float* c1_wk = (const float*)d_in[7],  *c1_bk = (const float*)d_in[8];
  const float* c1_wv = (const float*)d_in[9],  *c1_bv = (const float*)d_in[10];
  const float* c1_we = (const float*)d_in[11], *c1_be = (const float*)d_in[12];
  const float* c1_ws = (const float*)d_in[13], *c1_bs = (const float*)d_in[14];
  const float* c2_wq = (const float*)d_in[15], *c2_bq = (const float*)d_in[16];
  const float* c2_wk = (const float*)d_in[17], *c2_bk = (const float*)d_in[18];
  const float* c2_wv = (const float*)d_in[19], *c2_bv = (const float*)d_in[20];
  const float* c2_we = (const float*)d_in[21], *c2_be = (const float*)d_in[22];
  const float* c2_ws = (const float*)d_in[23], *c2_bs = (const float*)d_in[24];
  const float* w1 = (const float*)d_in[25], *b1 = (const float*)d_in[26];
  const float* w2 = (const float*)d_in[27], *b2 = (const float*)d_in[28];
  const float* w3 = (const float*)d_in[29], *b3 = (const float*)d_in[30];

  const int Nn = in_sizes[3];        // 50000
  const int Ee = in_sizes[1] / 2;    // 300000
  const int nrb = (Nn + 127) / 128;  // 391 row-blocks (gemm grid + padding)

  char* ws = (char*)d_ws;
  size_t off = 0;
  auto alloc = [&](size_t bytes) -> void* {
    void* p = ws + off;
    off += (bytes + 255) & ~(size_t)255;
    return p;
  };
  // xbf/h1bf padded to whole 128-row blocks (frag-order reads go to nrb*128)
  unsigned short* xbf   = (unsigned short*)alloc((size_t)nrb * 128 * 512 * 2);
  unsigned short* qbf   = (unsigned short*)alloc((size_t)Nn * 256 * 2);
  unsigned short* kbf   = (unsigned short*)alloc((size_t)Nn * 256 * 2);
  unsigned short* vbf   = (unsigned short*)alloc((size_t)Nn * 256 * 2);
  float*          skipf = (float*)alloc((size_t)Nn * 256 * 4);
  unsigned short* h1bf  = (unsigned short*)alloc((size_t)nrb * 128 * 256 * 2);
  unsigned short* Wcat1 = (unsigned short*)alloc((size_t)1024 * 512 * 2);
  float*          bcat1 = (float*)alloc(1024 * 4);
  unsigned short* Wcat2 = (unsigned short*)alloc((size_t)1024 * 256 * 2);
  float*          bcat2 = (float*)alloc(1024 * 4);
  int*            counts    = (int*)alloc((size_t)Nn * 4);
  int*            row_start = (int*)alloc((size_t)Nn * 4);
  int*            cursor    = (int*)alloc((size_t)Nn * 4);
  int*            srcs      = (int*)alloc((size_t)Ee * 4);
  int*            dsts      = (int*)alloc((size_t)Ee * 4);
  float*          ea_perm   = (float*)alloc((size_t)Ee * 6 * 4);
  float*          logits    = (float*)alloc((size_t)Ee * 4);   // becomes weights
  float*          zc        = (float*)alloc((size_t)Nn * 8 * 4);
  float*          ubar      = (float*)alloc((size_t)Nn * 8 * 4);
  int*            total     = (int*)alloc(256);
  float*          gap       = (float*)alloc((size_t)64 * 256 * 4);
  unsigned int*   gmp       = (unsigned int*)alloc((size_t)64 * 256 * 4);
  // h_acc (50k x 256 fp32 = 51.2 MB) ALIASES xbf (51.25 MB padded): xbf is
  // dead after gemm1; h_acc first touched after it. ~221 MB total.
  float* h_acc = (float*)xbf;

  const int* srcA = edge_index;
  const int* dstA = edge_index + Ee;

  hipMemsetAsync(counts, 0, (size_t)Nn * 4, stream);
  hipMemsetAsync(total, 0, 4, stream);
  hipMemsetAsync(gap, 0, (size_t)64 * 256 * 4, stream);
  hipMemsetAsync(gmp, 0, (size_t)64 * 256 * 4, stream);

  pack_weights<<<(1024 * 512 + 255) / 256, 256, 0, stream>>>(
      c1_wq, c1_wk, c1_wv, c1_ws, c1_bq, c1_bk, c1_bv, c1_bs, Wcat1, bcat1, 9);
  pack_weights<<<(1024 * 256 + 255) / 256, 256, 0, stream>>>(
      c2_wq, c2_wk, c2_wv, c2_ws, c2_bq, c2_bk, c2_bv, c2_bs, Wcat2, bcat2, 8);
  embed_gather<<<((Nn * 512) + 255) / 256, 256, 0, stream>>>(x_idx, emb, xbf, Nn * 512);
  count_dst<<<(Ee + 255) / 256, 256, 0, stream>>>(dstA, counts, Ee);
  alloc_rows<<<(Nn + 255) / 256, 256, 0, stream>>>(counts, row_start, cursor, total, Nn);
  scatter_edges<<<(Ee + 255) / 256, 256, 0, stream>>>(dstA, srcA, eattr, cursor,
                                                      srcs, dsts, ea_perm, Ee);

  // XCD-aware gemm grid: 8 XCD groups x max-row-blocks-per-XCD x 16 col-tiles
  const int rbmax = nrb / 8 + ((nrb % 8) ? 1 : 0);
  const int ggrid = 8 * rbmax * 16;
  const int egrid = (Ee + 31) / 32;
  const int sgrid = (Ee + CHK * 4 - 1) / (CHK * 4);
  const int ngrid = (Nn + 3) / 4;

  // layer 1
  gemm_qkvs<512><<<ggrid, 256, 0, stream>>>(xbf, Wcat1, bcat1, qbf, kbf, vbf,
                                            skipf, Nn, nrb);
  node_prep<<<ngrid, 256, 0, stream>>>(qbf, c1_we, c1_be, zc, Nn);
  edge_logits<<<egrid, 256, 0, stream>>>(srcs, dsts, ea_perm, qbf, kbf, zc, Ee, logits);
  node_softmax<<<ngrid, 256, 0, stream>>>(row_start, counts, ea_perm, logits, ubar, Nn);
  hipMemsetAsync(h_acc, 0, (size_t)Nn * 256 * 4, stream);   // xbf dead now
  edge_seg<<<sgrid, 256, 0, stream>>>(srcs, dsts, logits, vbf, Ee, h_acc);
  node_finalize<<<ngrid, 256, 0, stream>>>(h_acc, ubar, counts, skipf,
                                           c1_we, c1_be, Nn, 0, h1bf);

  // layer 2
  gemm_qkvs<256><<<ggrid, 256, 0, stream>>>(h1bf, Wcat2, bcat2, qbf, kbf, vbf,
                                            skipf, Nn, nrb);
  node_prep<<<ngrid, 256, 0, stream>>>(qbf, c2_we, c2_be, zc, Nn);
  edge_logits<<<egrid, 256, 0, stream>>>(srcs, dsts, ea_perm, qbf, kbf, zc, Ee, logits);
  node_softmax<<<ngrid, 256, 0, stream>>>(row_start, counts, ea_perm, logits, ubar, Nn);
  hipMemsetAsync(h_acc, 0, (size_t)Nn * 256 * 4, stream);
  edge_seg<<<sgrid, 256, 0, stream>>>(srcs, dsts, logits, vbf, Ee, h_acc);
  node_finalize<<<ngrid, 256, 0, stream>>>(h_acc, ubar, counts, skipf,
                                           c2_we, c2_be, Nn, 1, nullptr);

  // segmented pooling (batch sorted -> contiguous ranges), then MLP
  dim3 pg(64, 16);
  pool_reduce<<<pg, 256, 0, stream>>>(h_acc, batch, Nn, gap, gmp);
  pool_mlp<<<64, 256, 0, stream>>>(gap, gmp, batch, Nn, w1, b1, w2, b2, w3, b3,
                                   (float*)d_out);
}

// Round 12
// 792.942 us; speedup vs baseline: 1.5674x; 1.2441x over previous
//
#include <hip/hip_runtime.h>

typedef unsigned long long ull;
typedef __bf16 bf16x8 __attribute__((ext_vector_type(8)));
typedef float f32x4 __attribute__((ext_vector_type(4)));

__device__ __forceinline__ float bf2f(unsigned short u) {
  union { unsigned int i; float f; } c; c.i = ((unsigned int)u) << 16; return c.f;
}
__device__ __forceinline__ unsigned short f2bf(float f) {
  union { float f; unsigned int i; } c; c.f = f;
  unsigned int u = c.i;
  u += 0x7fffu + ((u >> 16) & 1u);
  return (unsigned short)(u >> 16);
}

// ---- pack 4x [256,K] fp32 weights -> bf16 B-FRAGMENT-ORDER + bias concat --
// Layout: Wcat[colt][ks][rg][lane][kj]  (fragment index OUTSIDE lane, so
// each 16B load instruction in gemm is lane-contiguous: 64x16B = 1KB burst).
__global__ __launch_bounds__(256) void pack_weights(
    const float* __restrict__ wq, const float* __restrict__ wk,
    const float* __restrict__ wv, const float* __restrict__ ws,
    const float* __restrict__ bq, const float* __restrict__ bk,
    const float* __restrict__ bv, const float* __restrict__ bs,
    unsigned short* __restrict__ Wcat, float* __restrict__ bcat, int logK) {
  int idx = blockIdx.x * 256 + threadIdx.x;
  if (idx < 1024) {
    int rr = idx >> 8, cc = idx & 255;
    const float* bp = (rr == 0) ? bq : (rr == 1) ? bk : (rr == 2) ? bv : bs;
    bcat[idx] = bp[cc];
  }
  int K = 1 << logK;
  if (idx >= (1024 << logK)) return;
  int kj = idx & 7;
  int lane = (idx >> 3) & 63;
  int rg = (idx >> 9) & 3;
  int ksbits = logK - 5;
  int ks = (idx >> 11) & ((1 << ksbits) - 1);
  int colt = idx >> (11 + ksbits);
  int quad = lane >> 4, lm = lane & 15;
  int o = colt * 64 + rg * 16 + lm;
  int k = ks * 32 + quad * 8 + kj;
  int rr = o >> 8, oo = o & 255;
  const float* wp = (rr == 0) ? wq : (rr == 1) ? wk : (rr == 2) ? wv : ws;
  Wcat[idx] = f2bf(wp[oo * K + k]);
}

// ---- embedding gather -> A-FRAGMENT-ORDER xbf (K=512) ---------------------
__global__ __launch_bounds__(256) void embed_gather(
    const int* __restrict__ x_idx, const float* __restrict__ emb,
    unsigned short* __restrict__ xbf, int total) {
  int idx = blockIdx.x * 256 + threadIdx.x;
  if (idx >= total) return;
  int n = idx >> 9, d = idx & 511, f = d >> 6, j = d & 63;
  int vi = x_idx[n * 8 + f];
  int n32 = n >> 5, lm = n & 15, half = (n >> 4) & 1;
  int ks = d >> 5, quad = (d >> 3) & 3, kj = d & 7;
  size_t a = (((size_t)(n32 * 16 + ks)) * 2 + half) * 512 + (quad * 16 + lm) * 8 + kj;
  xbf[a] = f2bf(emb[vi * 64 + j]);
}

// ---- CSR build ------------------------------------------------------------
__global__ __launch_bounds__(256) void count_dst(const int* __restrict__ dst,
                                                 int* __restrict__ counts, int E_) {
  int i = blockIdx.x * 256 + threadIdx.x;
  if (i < E_) atomicAdd(&counts[dst[i]], 1);
}

// NOTE: bases assigned by atomicAdd in arbitrary wave order -> row_start is
// a VALID CSR (disjoint, correct offsets) but NOT sorted by node index.
// No consumer may assume monotonicity (R11 bug).
__global__ __launch_bounds__(256) void alloc_rows(const int* __restrict__ counts,
                                                  int* __restrict__ row_start,
                                                  int* __restrict__ cursor,
                                                  int* __restrict__ total, int n) {
  int i = blockIdx.x * 256 + threadIdx.x;
  int lane = threadIdx.x & 63;
  int c = (i < n) ? counts[i] : 0;
  int incl = c;
#pragma unroll
  for (int off = 1; off < 64; off <<= 1) {
    int t = __shfl_up(incl, off, 64);
    if (lane >= off) incl += t;
  }
  int base = 0;
  if (lane == 63) base = atomicAdd(total, incl);
  base = __shfl(base, 63, 64);
  int st = base + incl - c;
  if (i < n) { row_start[i] = st; cursor[i] = st; }
}

// scatter edges into CSR order; materialize permuted src/dst ids and attrs
__global__ __launch_bounds__(256) void scatter_edges(
    const int* __restrict__ dst, const int* __restrict__ srcA,
    const float* __restrict__ eattr, int* __restrict__ cursor,
    int* __restrict__ srcs, int* __restrict__ dsts,
    float* __restrict__ ea_perm, int E_) {
  int i = blockIdx.x * 256 + threadIdx.x;
  if (i >= E_) return;
  int d = dst[i];
  int p = atomicAdd(&cursor[d], 1);
  srcs[p] = srcA[i];
  dsts[p] = d;
  const float* ea = eattr + (size_t)i * 6;
  float* eo = ea_perm + (size_t)p * 6;
  eo[0] = ea[0]; eo[1] = ea[1]; eo[2] = ea[2];
  eo[3] = ea[3]; eo[4] = ea[4]; eo[5] = ea[5];
}

// ---- fused QKVS GEMM, fully-coalesced fragment-order inputs ---------------
template <int K>
__global__ __launch_bounds__(256) void gemm_qkvs(
    const unsigned short* __restrict__ X, const unsigned short* __restrict__ W,
    const float* __restrict__ bcat,
    unsigned short* __restrict__ qout, unsigned short* __restrict__ kout,
    unsigned short* __restrict__ vout, float* __restrict__ sout,
    int Nn, int nrb) {
  const int l = blockIdx.x;
  const int xcd = l & 7, j = l >> 3;
  const int q = nrb >> 3, r = nrb & 7;
  const int cnt = q + (xcd < r ? 1 : 0);
  const int lrb = j >> 4, colt = j & 15;
  if (lrb >= cnt) return;
  const int m_blk = xcd * q + min(xcd, r) + lrb;

  const int wid = threadIdx.x >> 6;
  const int lane = threadIdx.x & 63;
  const int quad = lane >> 4, lm = lane & 15;
  const int m_base = m_blk * 128 + wid * 32;
  const int n_base = colt * 64;
  const size_t abase = (size_t)(m_blk * 4 + wid) * (K >> 5) * 1024 + lane * 8;
  const size_t bbase = (size_t)colt * (K >> 5) * 2048 + lane * 8;
  f32x4 acc[2][4] = {};
#pragma unroll 4
  for (int ks = 0; ks < (K >> 5); ks++) {
    const unsigned short* ap = X + abase + (size_t)ks * 1024;
    const unsigned short* bp = W + bbase + (size_t)ks * 2048;
    bf16x8 a0 = *(const bf16x8*)(ap);
    bf16x8 a1 = *(const bf16x8*)(ap + 512);
    bf16x8 b0 = *(const bf16x8*)(bp);
    bf16x8 b1 = *(const bf16x8*)(bp + 512);
    bf16x8 b2 = *(const bf16x8*)(bp + 1024);
    bf16x8 b3 = *(const bf16x8*)(bp + 1536);
    acc[0][0] = __builtin_amdgcn_mfma_f32_16x16x32_bf16(a0, b0, acc[0][0], 0, 0, 0);
    acc[0][1] = __builtin_amdgcn_mfma_f32_16x16x32_bf16(a0, b1, acc[0][1], 0, 0, 0);
    acc[0][2] = __builtin_amdgcn_mfma_f32_16x16x32_bf16(a0, b2, acc[0][2], 0, 0, 0);
    acc[0][3] = __builtin_amdgcn_mfma_f32_16x16x32_bf16(a0, b3, acc[0][3], 0, 0, 0);
    acc[1][0] = __builtin_amdgcn_mfma_f32_16x16x32_bf16(a1, b0, acc[1][0], 0, 0, 0);
    acc[1][1] = __builtin_amdgcn_mfma_f32_16x16x32_bf16(a1, b1, acc[1][1], 0, 0, 0);
    acc[1][2] = __builtin_amdgcn_mfma_f32_16x16x32_bf16(a1, b2, acc[1][2], 0, 0, 0);
    acc[1][3] = __builtin_amdgcn_mfma_f32_16x16x32_bf16(a1, b3, acc[1][3], 0, 0, 0);
  }
#pragma unroll
  for (int mi = 0; mi < 2; mi++) {
#pragma unroll
    for (int r2 = 0; r2 < 4; r2++) {
      int row = m_base + mi * 16 + quad * 4 + r2;
      if (row >= Nn) continue;
      size_t rb = (size_t)row * 256;
#pragma unroll
      for (int ni = 0; ni < 4; ni++) {
        int col = n_base + ni * 16 + lm;
        float v = acc[mi][ni][r2] + bcat[col];
        int reg = col >> 8, c = col & 255;
        if (reg == 0)       qout[rb + c] = f2bf(v * 0.0625f);
        else if (reg == 1)  kout[rb + c] = f2bf(v);
        else if (reg == 2)  vout[rb + c] = f2bf(v);
        else                sout[rb + c] = v;
      }
    }
  }
}

// ---- node_prep: z[n] = We^T q[n] (6), c[n] = q[n].be -> zc[n][8] ----------
__global__ __launch_bounds__(256) void node_prep(
    const unsigned short* __restrict__ qv,
    const float* __restrict__ we, const float* __restrict__ be,
    float* __restrict__ zc, int Nn) {
  __shared__ float we_s[1536];
  __shared__ float be_s[256];
  for (int i = threadIdx.x; i < 1536; i += 256) we_s[i] = we[i];
  be_s[threadIdx.x] = be[threadIdx.x];
  __syncthreads();
  int wid = threadIdx.x >> 6, lane = threadIdx.x & 63;
  int n = blockIdx.x * 4 + wid;
  if (n >= Nn) return;
  int j0 = lane * 4;
  ull uq = *(const ull*)(qv + (size_t)n * 256 + j0);
  float q0 = bf2f((unsigned short)uq), q1 = bf2f((unsigned short)(uq >> 16));
  float q2 = bf2f((unsigned short)(uq >> 32)), q3 = bf2f((unsigned short)(uq >> 48));
  float part[7];
#pragma unroll
  for (int t = 0; t < 6; t++) {
    part[t] = we_s[(j0 + 0) * 6 + t] * q0 + we_s[(j0 + 1) * 6 + t] * q1
            + we_s[(j0 + 2) * 6 + t] * q2 + we_s[(j0 + 3) * 6 + t] * q3;
  }
  part[6] = be_s[j0] * q0 + be_s[j0 + 1] * q1 + be_s[j0 + 2] * q2 + be_s[j0 + 3] * q3;
#pragma unroll
  for (int off = 32; off > 0; off >>= 1) {
#pragma unroll
    for (int t = 0; t < 7; t++) part[t] += __shfl_xor(part[t], off, 64);
  }
  if (lane == 0) {
    float* zp = zc + (size_t)n * 8;
#pragma unroll
    for (int t = 0; t < 7; t++) zp[t] = part[t];
    zp[7] = 0.f;
  }
}

__device__ __forceinline__ float dot4(ull uq, ull uk) {
  return bf2f((unsigned short)uq) * bf2f((unsigned short)uk)
       + bf2f((unsigned short)(uq >> 16)) * bf2f((unsigned short)(uk >> 16))
       + bf2f((unsigned short)(uq >> 32)) * bf2f((unsigned short)(uk >> 32))
       + bf2f((unsigned short)(uq >> 48)) * bf2f((unsigned short)(uk >> 48));
}

#define SEL8_I(a, t) ((t)==0?(a)[0]:(t)==1?(a)[1]:(t)==2?(a)[2]:(t)==3?(a)[3]:(t)==4?(a)[4]:(t)==5?(a)[5]:(t)==6?(a)[6]:(a)[7])

// ---- P1: edge-parallel logits = q[dst].k[src] + z[dst].u + c[dst] ---------
__global__ __launch_bounds__(256) void edge_logits(
    const int* __restrict__ srcs, const int* __restrict__ dsts,
    const float* __restrict__ ea_perm,
    const unsigned short* __restrict__ qv, const unsigned short* __restrict__ kv,
    const float* __restrict__ zc, int E_, float* __restrict__ logits) {
  int wid = threadIdx.x >> 6, lane = threadIdx.x & 63;
  int p0 = (blockIdx.x * 4 + wid) * 8;
  if (p0 >= E_) return;
  int j0 = lane * 4;
  int s_[8], d_[8];
  if (p0 + 8 <= E_) {
    int4 sa = *(const int4*)(srcs + p0), sb = *(const int4*)(srcs + p0 + 4);
    int4 da = *(const int4*)(dsts + p0), db = *(const int4*)(dsts + p0 + 4);
    s_[0] = sa.x; s_[1] = sa.y; s_[2] = sa.z; s_[3] = sa.w;
    s_[4] = sb.x; s_[5] = sb.y; s_[6] = sb.z; s_[7] = sb.w;
    d_[0] = da.x; d_[1] = da.y; d_[2] = da.z; d_[3] = da.w;
    d_[4] = db.x; d_[5] = db.y; d_[6] = db.z; d_[7] = db.w;
  } else {
#pragma unroll
    for (int t = 0; t < 8; t++) {
      int pp = min(p0 + t, E_ - 1);
      s_[t] = srcs[pp]; d_[t] = dsts[pp];
    }
  }
  ull uk[8], uq[8];
#pragma unroll
  for (int t = 0; t < 8; t++) uk[t] = *(const ull*)(kv + (size_t)s_[t] * 256 + j0);
#pragma unroll
  for (int t = 0; t < 8; t++) uq[t] = *(const ull*)(qv + (size_t)d_[t] * 256 + j0);
  float pv[8];
#pragma unroll
  for (int t = 0; t < 8; t++) pv[t] = dot4(uq[t], uk[t]);
#pragma unroll
  for (int off = 32; off > 0; off >>= 1) {
#pragma unroll
    for (int t = 0; t < 8; t++) pv[t] += __shfl_xor(pv[t], off, 64);
  }
  // lane t (t<8) finalizes edge t: + z[dst].u + c[dst]
  if (lane < 8 && p0 + lane < E_) {
    int t = lane;
    int dd = SEL8_I(d_, t);
    float pvt = SEL8_I(pv, t);
    const float* zp = zc + (size_t)dd * 8;
    const float* u = ea_perm + (size_t)(p0 + t) * 6;
    float zd = zp[0] * u[0] + zp[1] * u[1] + zp[2] * u[2]
             + zp[3] * u[3] + zp[4] * u[4] + zp[5] * u[5] + zp[6];
    logits[p0 + t] = pvt + zd;
  }
}

// ---- P2: per-node softmax; overwrite logits with weights; also ubar -------
__global__ __launch_bounds__(256) void node_softmax(
    const int* __restrict__ row_start, const int* __restrict__ counts,
    const float* __restrict__ ea_perm,
    float* __restrict__ logits, float* __restrict__ ubar, int Nn) {
  int wid = threadIdx.x >> 6, lane = threadIdx.x & 63;
  int n = blockIdx.x * 4 + wid;
  if (n >= Nn) return;
  int beg = row_start[n], cnt = counts[n];
  if (cnt == 0) return;
  float lm = -INFINITY;
  for (int b = lane; b < cnt; b += 64) lm = fmaxf(lm, logits[beg + b]);
#pragma unroll
  for (int off = 32; off > 0; off >>= 1) lm = fmaxf(lm, __shfl_xor(lm, off, 64));
  float se = 0.f;
  for (int b = lane; b < cnt; b += 64) se += __expf(logits[beg + b] - lm);
#pragma unroll
  for (int off = 32; off > 0; off >>= 1) se += __shfl_xor(se, off, 64);
  float inv = 1.f / se;
  float u0 = 0.f, u1 = 0.f, u2 = 0.f, u3 = 0.f, u4 = 0.f, u5 = 0.f;
  for (int b = lane; b < cnt; b += 64) {
    int p = beg + b;
    float w = __expf(logits[p] - lm) * inv;
    logits[p] = w;
    const float* up = ea_perm + (size_t)p * 6;
    u0 += w * up[0]; u1 += w * up[1]; u2 += w * up[2];
    u3 += w * up[3]; u4 += w * up[4]; u5 += w * up[5];
  }
#pragma unroll
  for (int off = 32; off > 0; off >>= 1) {
    u0 += __shfl_xor(u0, off, 64); u1 += __shfl_xor(u1, off, 64);
    u2 += __shfl_xor(u2, off, 64); u3 += __shfl_xor(u3, off, 64);
    u4 += __shfl_xor(u4, off, 64); u5 += __shfl_xor(u5, off, 64);
  }
  if (lane == 0) {
    float* up = ubar + (size_t)n * 8;
    up[0] = u0; up[1] = u1; up[2] = u2; up[3] = u3; up[4] = u4; up[5] = u5;
  }
}

// ---- P3: ATOMIC-FREE node-owned weighted v-sum ----------------------------
// Wave w owns nodes [8w, 8w+8) by NODE INDEX (no sortedness assumption on
// row_start -- R11's binary-search over atomic-ordered bases was the bug).
// Each cnt>0 node gets exactly ONE direct float4 store. Zero atomics,
// zero pre-memset (cnt==0 rows never read downstream).
#define NPW 8
__global__ __launch_bounds__(256) void edge_seg(
    const int* __restrict__ srcs, const int* __restrict__ row_start,
    const int* __restrict__ counts, const float* __restrict__ wgt,
    const unsigned short* __restrict__ vv, int Nn,
    float* __restrict__ h_acc) {
  int wave = blockIdx.x * 4 + (threadIdx.x >> 6);
  int lane = threadIdx.x & 63;
  int n0 = wave * NPW;
  if (n0 >= Nn) return;
  int n1 = min(n0 + NPW, Nn);
  int j0 = lane * 4;
  for (int n = n0; n < n1; n++) {
    int cnt = counts[n];
    if (cnt == 0) continue;
    int beg = row_start[n];
    float a0 = 0.f, a1 = 0.f, a2 = 0.f, a3 = 0.f;
    for (int i0 = 0; i0 < cnt; i0 += 8) {
      int m = cnt - i0; if (m > 8) m = 8;
      float w8[8];
      int s8[8];
#pragma unroll
      for (int t = 0; t < 8; t++) {
        int pp = beg + i0 + ((t < m) ? t : (m - 1));
        w8[t] = (t < m) ? wgt[pp] : 0.f;
        s8[t] = srcs[pp];
      }
      ull uv[8];
#pragma unroll
      for (int t = 0; t < 8; t++)
        uv[t] = *(const ull*)(vv + (size_t)s8[t] * 256 + j0);
#pragma unroll
      for (int t = 0; t < 8; t++) {
        float ww = w8[t];
        a0 += ww * bf2f((unsigned short)uv[t]);
        a1 += ww * bf2f((unsigned short)(uv[t] >> 16));
        a2 += ww * bf2f((unsigned short)(uv[t] >> 32));
        a3 += ww * bf2f((unsigned short)(uv[t] >> 48));
      }
    }
    float4 o; o.x = a0; o.y = a1; o.z = a2; o.w = a3;
    *(float4*)(h_acc + (size_t)n * 256 + j0) = o;
  }
}

// ---- P4: streaming finalize: h = relu(h_acc + We*ubar + be*[cnt>0] + skip)
// cnt==0 rows of h_acc are NEVER read (stale garbage allowed -> no memset).
// mode 0: write h bf16 to hout in A-FRAGMENT-ORDER (K=256, gemm2 input).
// mode 1: write h fp32 IN PLACE into h_acc (pool_reduce consumes).
__global__ __launch_bounds__(256) void node_finalize(
    float* __restrict__ h_acc, const float* __restrict__ ubar,
    const int* __restrict__ counts, const float* __restrict__ skipv,
    const float* __restrict__ we, const float* __restrict__ be,
    int Nn, int mode,
    unsigned short* __restrict__ hout) {
  __shared__ float we_s[1536];
  __shared__ float be_s[256];
  for (int i = threadIdx.x; i < 1536; i += 256) we_s[i] = we[i];
  be_s[threadIdx.x] = be[threadIdx.x];
  __syncthreads();
  int wid = threadIdx.x >> 6, lane = threadIdx.x & 63;
  int n = blockIdx.x * 4 + wid;
  if (n >= Nn) return;
  int j0 = lane * 4;
  int cnt = counts[n];
  float4 skv = *(const float4*)(skipv + (size_t)n * 256 + j0);
  float4 ha = make_float4(0.f, 0.f, 0.f, 0.f);
  float e[4] = {0.f, 0.f, 0.f, 0.f};
  if (cnt > 0) {
    ha = *(const float4*)(h_acc + (size_t)n * 256 + j0);
    float4 u0 = *(const float4*)(ubar + (size_t)n * 8);
    float4 u1 = *(const float4*)(ubar + (size_t)n * 8 + 4);
#pragma unroll
    for (int r = 0; r < 4; r++) {
      int d = j0 + r;
      e[r] = be_s[d]
           + we_s[d * 6 + 0] * u0.x + we_s[d * 6 + 1] * u0.y + we_s[d * 6 + 2] * u0.z
           + we_s[d * 6 + 3] * u0.w + we_s[d * 6 + 4] * u1.x + we_s[d * 6 + 5] * u1.y;
    }
  }
  float h0 = fmaxf(ha.x + e[0] + skv.x, 0.f);
  float h1 = fmaxf(ha.y + e[1] + skv.y, 0.f);
  float h2 = fmaxf(ha.z + e[2] + skv.z, 0.f);
  float h3 = fmaxf(ha.w + e[3] + skv.w, 0.f);
  if (mode == 0) {
    ull hv = (ull)f2bf(h0) | ((ull)f2bf(h1) << 16) | ((ull)f2bf(h2) << 32) | ((ull)f2bf(h3) << 48);
    // A-frag-order address (K=256)
    int n32 = n >> 5, lmn = n & 15, halfn = (n >> 4) & 1;
    int ks = lane >> 3, quadc = (lane >> 1) & 3, kjc = (lane & 1) * 4;
    size_t a = (((size_t)(n32 * 8 + ks)) * 2 + halfn) * 512 + (quadc * 16 + lmn) * 8 + kjc;
    *(ull*)(hout + a) = hv;
  } else {
    float4 o; o.x = h0; o.y = h1; o.z = h2; o.w = h3;
    *(float4*)(h_acc + (size_t)n * 256 + j0) = o;
  }
}

// ---- P5: segmented pooling over sorted batch (contiguous node ranges) -----
__global__ __launch_bounds__(256) void pool_reduce(
    const float* __restrict__ hfin, const int* __restrict__ batch, int Nn,
    float* __restrict__ gap, unsigned int* __restrict__ gmp) {
  int g = blockIdx.x, s = blockIdx.y, t = threadIdx.x;
  __shared__ int st_s, en_s;
  if (t == 0) {
    int lo = 0, hi = Nn;
    while (lo < hi) { int mid = (lo + hi) >> 1; if (batch[mid] < g) lo = mid + 1; else hi = mid; }
    st_s = lo;
    lo = 0; hi = Nn;
    while (lo < hi) { int mid = (lo + hi) >> 1; if (batch[mid] < g + 1) lo = mid + 1; else hi = mid; }
    en_s = lo;
  }
  __syncthreads();
  int st = st_s, en = en_s;
  int len = en - st;
  if (len <= 0) return;
  int nsplit = gridDim.y;
  int chunk = (len + nsplit - 1) / nsplit;
  int a = st + s * chunk;
  int b = min(a + chunk, en);
  if (a >= b) return;
  float acc = 0.f, mx = 0.f;  // h >= 0 (relu)
  for (int n = a; n < b; n++) {
    float v = hfin[(size_t)n * 256 + t];
    acc += v;
    mx = fmaxf(mx, v);
  }
  atomicAdd(&gap[(size_t)g * 256 + t], acc);
  atomicMax(&gmp[(size_t)g * 256 + t], __float_as_uint(mx));
}

// ---- per-graph pooling finalize + 3-layer MLP + sigmoid -------------------
__global__ __launch_bounds__(256) void pool_mlp(
    const float* __restrict__ gap, const unsigned int* __restrict__ gmp,
    const int* __restrict__ batch, int Nn,
    const float* __restrict__ w1, const float* __restrict__ b1,
    const float* __restrict__ w2, const float* __restrict__ b2,
    const float* __restrict__ w3, const float* __restrict__ b3,
    float* __restrict__ out) {
  int g = blockIdx.x, t = threadIdx.x;
  __shared__ float r[512];
  __shared__ float o1[256];
  __shared__ float o2[128];
  __shared__ float red[256];
  __shared__ int cnt_s;
  if (t == 0) {
    int lo = 0, hi = Nn;
    while (lo < hi) { int mid = (lo + hi) >> 1; if (batch[mid] < g) lo = mid + 1; else hi = mid; }
    int st = lo;
    lo = 0; hi = Nn;
    while (lo < hi) { int mid = (lo + hi) >> 1; if (batch[mid] < g + 1) lo = mid + 1; else hi = mid; }
    cnt_s = lo - st;
  }
  __syncthreads();
  float inv = 1.f / fmaxf((float)cnt_s, 1.f);
  r[t] = gap[(size_t)g * 256 + t] * inv;
  r[256 + t] = __uint_as_float(gmp[(size_t)g * 256 + t]);
  __syncthreads();
  {
    float a = b1[t];
    const float* wr = w1 + (size_t)t * 512;
    for (int k = 0; k < 512; k++) a += wr[k] * r[k];
    o1[t] = fmaxf(a, 0.f);
  }
  __syncthreads();
  if (t < 128) {
    float a = b2[t];
    const float* wr = w2 + (size_t)t * 256;
    for (int k = 0; k < 256; k++) a += wr[k] * o1[k];
    o2[t] = fmaxf(a, 0.f);
  }
  __syncthreads();
  red[t] = (t < 128) ? w3[t] * o2[t] : 0.f;
  __syncthreads();
  for (int s = 128; s > 0; s >>= 1) {
    if (t < s) red[t] += red[t + s];
    __syncthreads();
  }
  if (t == 0) out[g] = 1.f / (1.f + expf(-(red[0] + b3[0])));
}

// ---------------------------------------------------------------------------
extern "C" void kernel_launch(void* const* d_in, const int* in_sizes, int n_in,
                              void* d_out, int out_size, void* d_ws, size_t ws_size,
                              hipStream_t stream) {
  const int* x_idx      = (const int*)d_in[0];
  const int* edge_index = (const int*)d_in[1];
  const float* eattr    = (const float*)d_in[2];
  const int* batch      = (const int*)d_in[3];
  const float* emb      = (const float*)d_in[4];
  const float* c1_wq = (const float*)d_in[5],  *c1_bq = (const float*)d_in[6];
  const float* c1_wk = (const float*)d_in[7],  *c1_bk = (const float*)d_in[8];
  const float* c1_wv = (const float*)d_in[9],  *c1_bv = (const float*)d_in[10];
  const float* c1_we = (const float*)d_in[11], *c1_be = (const float*)d_in[12];
  const float* c1_ws = (const float*)d_in[13], *c1_bs = (const float*)d_in[14];
  const float* c2_wq = (const float*)d_in[15], *c2_bq = (const float*)d_in[16];
  const float* c2_wk = (const float*)d_in[17], *c2_bk = (const float*)d_in[18];
  const float* c2_wv = (const float*)d_in[19], *c2_bv = (const float*)d_in[20];
  const float* c2_we = (const float*)d_in[21], *c2_be = (const float*)d_in[22];
  const float* c2_ws = (const float*)d_in[23], *c2_bs = (const float*)d_in[24];
  const float* w1 = (const float*)d_in[25], *b1 = (const float*)d_in[26];
  const float* w2 = (const float*)d_in[27], *b2 = (const float*)d_in[28];
  const float* w3 = (const float*)d_in[29], *b3 = (const float*)d_in[30];

  const int Nn = in_sizes[3];        // 50000
  const int Ee = in_sizes[1] / 2;    // 300000
  const int nrb = (Nn + 127) / 128;  // 391 row-blocks (gemm grid + padding)

  char* ws = (char*)d_ws;
  size_t off = 0;
  auto alloc = [&](size_t bytes) -> void* {
    void* p = ws + off;
    off += (bytes + 255) & ~(size_t)255;
    return p;
  };
  // xbf/h1bf padded to whole 128-row blocks (frag-order reads go to nrb*128)
  unsigned short* xbf   = (unsigned short*)alloc((size_t)nrb * 128 * 512 * 2);
  unsigned short* qbf   = (unsigned short*)alloc((size_t)Nn * 256 * 2);
  unsigned short* kbf   = (unsigned short*)alloc((size_t)Nn * 256 * 2);
  unsigned short* vbf   = (unsigned short*)alloc((size_t)Nn * 256 * 2);
  float*          skipf = (float*)alloc((size_t)Nn * 256 * 4);
  unsigned short* h1bf  = (unsigned short*)alloc((size_t)nrb * 128 * 256 * 2);
  unsigned short* Wcat1 = (unsigned short*)alloc((size_t)1024 * 512 * 2);
  float*          bcat1 = (float*)alloc(1024 * 4);
  unsigned short* Wcat2 = (unsigned short*)alloc((size_t)1024 * 256 * 2);
  float*          bcat2 = (float*)alloc(1024 * 4);
  int*            counts    = (int*)alloc((size_t)Nn * 4);
  int*            row_start = (int*)alloc((size_t)Nn * 4);
  int*            cursor    = (int*)alloc((size_t)Nn * 4);
  int*            srcs      = (int*)alloc((size_t)Ee * 4);
  int*            dsts      = (int*)alloc((size_t)Ee * 4);
  float*          ea_perm   = (float*)alloc((size_t)Ee * 6 * 4);
  float*          logits    = (float*)alloc((size_t)Ee * 4);   // becomes weights
  float*          zc        = (float*)alloc((size_t)Nn * 8 * 4);
  float*          ubar      = (float*)alloc((size_t)Nn * 8 * 4);
  int*            total     = (int*)alloc(256);
  float*          gap       = (float*)alloc((size_t)64 * 256 * 4);
  unsigned int*   gmp       = (unsigned int*)alloc((size_t)64 * 256 * 4);
  // h_acc (50k x 256 fp32 = 51.2 MB) ALIASES xbf (51.25 MB padded): xbf is
  // dead after gemm1; h_acc first touched after it. ~221 MB total.
  float* h_acc = (float*)xbf;

  const int* srcA = edge_index;
  const int* dstA = edge_index + Ee;

  hipMemsetAsync(counts, 0, (size_t)Nn * 4, stream);
  hipMemsetAsync(total, 0, 4, stream);
  hipMemsetAsync(gap, 0, (size_t)64 * 256 * 4, stream);
  hipMemsetAsync(gmp, 0, (size_t)64 * 256 * 4, stream);

  pack_weights<<<(1024 * 512 + 255) / 256, 256, 0, stream>>>(
      c1_wq, c1_wk, c1_wv, c1_ws, c1_bq, c1_bk, c1_bv, c1_bs, Wcat1, bcat1, 9);
  pack_weights<<<(1024 * 256 + 255) / 256, 256, 0, stream>>>(
      c2_wq, c2_wk, c2_wv, c2_ws, c2_bq, c2_bk, c2_bv, c2_bs, Wcat2, bcat2, 8);
  embed_gather<<<((Nn * 512) + 255) / 256, 256, 0, stream>>>(x_idx, emb, xbf, Nn * 512);
  count_dst<<<(Ee + 255) / 256, 256, 0, stream>>>(dstA, counts, Ee);
  alloc_rows<<<(Nn + 255) / 256, 256, 0, stream>>>(counts, row_start, cursor, total, Nn);
  scatter_edges<<<(Ee + 255) / 256, 256, 0, stream>>>(dstA, srcA, eattr, cursor,
                                                      srcs, dsts, ea_perm, Ee);

  // XCD-aware gemm grid: 8 XCD groups x max-row-blocks-per-XCD x 16 col-tiles
  const int rbmax = nrb / 8 + ((nrb % 8) ? 1 : 0);
  const int ggrid = 8 * rbmax * 16;
  const int egrid = (Ee + 31) / 32;
  const int sgrid = (Nn + NPW * 4 - 1) / (NPW * 4);  // node-owned edge_seg
  const int ngrid = (Nn + 3) / 4;

  // layer 1
  gemm_qkvs<512><<<ggrid, 256, 0, stream>>>(xbf, Wcat1, bcat1, qbf, kbf, vbf,
                                            skipf, Nn, nrb);
  node_prep<<<ngrid, 256, 0, stream>>>(qbf, c1_we, c1_be, zc, Nn);
  edge_logits<<<egrid, 256, 0, stream>>>(srcs, dsts, ea_perm, qbf, kbf, zc, Ee, logits);
  node_softmax<<<ngrid, 256, 0, stream>>>(row_start, counts, ea_perm, logits, ubar, Nn);
  edge_seg<<<sgrid, 256, 0, stream>>>(srcs, row_start, counts, logits, vbf,
                                      Nn, h_acc);
  node_finalize<<<ngrid, 256, 0, stream>>>(h_acc, ubar, counts, skipf,
                                           c1_we, c1_be, Nn, 0, h1bf);

  // layer 2
  gemm_qkvs<256><<<ggrid, 256, 0, stream>>>(h1bf, Wcat2, bcat2, qbf, kbf, vbf,
                                            skipf, Nn, nrb);
  node_prep<<<ngrid, 256, 0, stream>>>(qbf, c2_we, c2_be, zc, Nn);
  edge_logits<<<egrid, 256, 0, stream>>>(srcs, dsts, ea_perm, qbf, kbf, zc, Ee, logits);
  node_softmax<<<ngrid, 256, 0, stream>>>(row_start, counts, ea_perm, logits, ubar, Nn);
  edge_seg<<<sgrid, 256, 0, stream>>>(srcs, row_start, counts, logits, vbf,
                                      Nn, h_acc);
  node_finalize<<<ngrid, 256, 0, stream>>>(h_acc, ubar, counts, skipf,
                                           c2_we, c2_be, Nn, 1, nullptr);

  // segmented pooling (batch sorted -> contiguous ranges), then MLP
  dim3 pg(64, 16);
  pool_reduce<<<pg, 256, 0, stream>>>(h_acc, batch, Nn, gap, gmp);
  pool_mlp<<<64, 256, 0, stream>>>(gap, gmp, batch, Nn, w1, b1, w2, b2, w3, b3,
                                   (float*)d_out);
}